// Round 10
// baseline (559.321 us; speedup 1.0000x reference)
//
#include <hip/hip_runtime.h>

typedef __attribute__((ext_vector_type(8))) short bf16x8;
typedef __attribute__((ext_vector_type(4))) float f32x4;

#define EPS 1e-5f
#define B 8
#define C 256
#define NPIX 4096      // 64*64
#define NCH 144        // rows: 0..63 q_bn, 64..127 v_bn, 128..143 kf(raw)
#define ROW_V 64
#define ROW_KF 128
#define PAD 11
#define VH_WORDS 3840  // 4-byte words reserved per (v,b) halo (3784 used)

// workspace layout (float offsets)
#define WP_OFF    0u          // Wt transposed: 256*144 = 36864
#define BIAS_OFF  36864u      // 144
#define PROJ_OFF  37120u      // 8*144*4096 = 4718592
#define RMAX_OFF  4755712u    // now S: 128 softmax denominators (+128 pad)
#define LC_OFF    4755968u    // 8*16*64 = 8192 (raw, divided by S in conv)
#define ET_OFF    4764160u    // E variants: 94208 ushort = 47104 floats
#define QT_OFF    4811264u    // qT: 8*64*4096 = 2097152 (wtA borrows its head pre-qtrans)
#define OUTT_OFF  6908416u    // outT: 8*256*4096 = 8388608 (end 15297024 floats)
#define WS_NEED_QT    6908416u
#define WS_NEED_FULL  15297024u

__device__ inline short f2bf(float f) {
  unsigned u = __float_as_uint(f);
  return (short)((u + 0x7fffu + ((u >> 16) & 1u)) >> 16);
}

// ---------------- 1) fused prep: blocks 0..143 fold BN into Wt; 144..511 build E ----
__global__ __launch_bounds__(256) void k_prep(
    const float* __restrict__ Wq, const float* __restrict__ qg, const float* __restrict__ qb,
    const float* __restrict__ qm, const float* __restrict__ qv,
    const float* __restrict__ Wk, const float* __restrict__ Wv,
    const float* __restrict__ vg, const float* __restrict__ vb,
    const float* __restrict__ vm, const float* __restrict__ vvar,
    const float* __restrict__ emb,
    float* __restrict__ Wt, float* __restrict__ biasp, ushort* __restrict__ etw) {
  int t = threadIdx.x;
  if (blockIdx.x < 144) {
    int o = blockIdx.x;   // 0..143
    const float* src; float s, bias;
    if (o < 64) {
      s = qg[o] * rsqrtf(qv[o] + EPS); bias = qb[o] - qm[o] * s; src = Wq + o * C;
    } else if (o < 128) {
      int i = o - 64;
      s = vg[i] * rsqrtf(vvar[i] + EPS); bias = vb[i] - vm[i] * s; src = Wv + i * C;
    } else {
      int i = o - 128; s = 1.f; bias = 0.f; src = Wk + i * C;
    }
    Wt[t * NCH + o] = src[t] * s;
    if (t == 0) biasp[o] = bias;
  } else {
    int i = (blockIdx.x - 144) * 256 + t;   // 0..94207
    int s = i / 11776;
    int r = i % 11776;
    int dy = r / 512;
    int l = (r / 8) % 64;
    int jj = r % 8;
    int f = l & 15, q = l >> 4;
    int dx = q * 8 + jj - s;
    float val = (dx >= 0 && dx < 23) ? emb[f * 529 + dy * 23 + dx] : 0.f;
    unsigned u = __float_as_uint(val);
    etw[i] = (ushort)((u + 0x7fffu + ((u >> 16) & 1u)) >> 16);
  }
}

// ---------------- 1c) prepack Wt into MFMA A-fragment order (bf16) ----------------
__global__ __launch_bounds__(256) void k_wprep(
    const float* __restrict__ Wt, ushort* __restrict__ wtA) {
  int i = blockIdx.x * 256 + threadIdx.x;   // 0..4607
  int mt = i >> 9;
  int rest = i & 511;
  int kt = rest >> 6;
  int lane = rest & 63;
  int m = mt * 16 + (lane & 15);
  int c0 = kt * 32 + (lane >> 4) * 8;
  ushort* dst = wtA + (size_t)i * 8;
  #pragma unroll
  for (int j = 0; j < 8; j++) {
    float v = Wt[(c0 + j) * NCH + m];
    unsigned u = __float_as_uint(v);
    dst[j] = (ushort)((u + 0x7fffu + ((u >> 16) & 1u)) >> 16);
  }
}

// ---------------- 2) projection as MFMA GEMM: proj = Wt^T x + bias ----------------
__global__ __launch_bounds__(256) void k_projm(
    const float* __restrict__ x, const ushort* __restrict__ wtA,
    const float* __restrict__ biasp, float* __restrict__ proj) {
  int ntile = blockIdx.x;  // 0..63
  int b = blockIdx.y;
  int t = threadIdx.x;
  int lane = t & 63, w = t >> 6;
  int px = ntile * 64 + w * 16 + (lane & 15);
  int kq = lane >> 4;
  const float* xb = x + (size_t)b * C * NPIX + px;
  const bf16x8* A = (const bf16x8*)wtA;
  f32x4 acc[9];
  #pragma unroll
  for (int i = 0; i < 9; i++) acc[i] = (f32x4)(0.f);
  #pragma unroll 2
  for (int kt = 0; kt < 8; kt++) {
    int c0 = kt * 32 + kq * 8;
    bf16x8 bb;
    #pragma unroll
    for (int j = 0; j < 8; j++) bb[j] = f2bf(xb[(size_t)(c0 + j) * NPIX]);
    #pragma unroll
    for (int mt = 0; mt < 9; mt++) {
      bf16x8 a = A[(mt * 8 + kt) * 64 + lane];
      acc[mt] = __builtin_amdgcn_mfma_f32_16x16x32_bf16(a, bb, acc[mt], 0, 0, 0);
    }
  }
  float* pb = proj + (size_t)b * NCH * NPIX + px;
  #pragma unroll
  for (int mt = 0; mt < 9; mt++) {
    #pragma unroll
    for (int r = 0; r < 4; r++) {
      int ch = mt * 16 + kq * 4 + r;
      pb[(size_t)ch * NPIX] = acc[mt][r] + biasp[ch];
    }
  }
}

// ---------------- 2-fallback) VALU projection (mode 0 only) ----------
__global__ __launch_bounds__(256) void k_proj(
    const float* __restrict__ x, const float* __restrict__ Wt,
    const float* __restrict__ biasp, float* __restrict__ proj) {
  int tile = blockIdx.x;  // 0..15
  int g = blockIdx.y;     // 0..7 (18 ch each)
  int b = blockIdx.z;
  int t = threadIdx.x;
  int px = tile * 256 + t;
  const float* xb = x + (size_t)b * C * NPIX + px;
  float acc[18];
  #pragma unroll
  for (int i = 0; i < 18; i++) acc[i] = 0.f;
  #pragma unroll 4
  for (int c = 0; c < C; c++) {
    float xv = xb[(size_t)c * NPIX];
    const float* wrow = Wt + c * NCH + g * 18;   // uniform -> s_load
    #pragma unroll
    for (int i = 0; i < 18; i++) acc[i] += xv * wrow[i];
  }
  float* ob = proj + ((size_t)b * NCH + g * 18) * NPIX + px;
  #pragma unroll
  for (int i = 0; i < 18; i++) ob[(size_t)i * NPIX] = acc[i] + biasp[g * 18 + i];
}

// ---------------- 2b) transpose q rows: proj[b][ch][p] -> qT[b][ch][s*512+i] ----------
__global__ __launch_bounds__(256) void k_qtrans(
    const float* __restrict__ proj, float* __restrict__ qT) {
  int ch = blockIdx.x, b = blockIdx.y, t = threadIdx.x;
  __shared__ float buf[4608];
  const float* src = proj + ((size_t)b * NCH + ch) * NPIX;
  for (int it = 0; it < 16; it++) {
    int p = it * 256 + t;
    buf[p + (p >> 3)] = src[p];
  }
  __syncthreads();
  float* dst = qT + ((size_t)b * 64 + ch) * NPIX;
  for (int it = 0; it < 16; it++) {
    int idx = it * 256 + t;           // s*512 + i
    int s = idx >> 9, i = idx & 511;
    int p = (i >> 3) * 64 + (i & 7) * 8 + s;
    dst[idx] = buf[p + (p >> 3)];
  }
}

// ---------------- 2c) prebuild bf16 halos: one 86x88 halo per (v,b) ----------------
__global__ __launch_bounds__(256) void k_vhalo(
    const float* __restrict__ proj, uint* __restrict__ vhg) {
  int v = blockIdx.x, b = blockIdx.y, t = threadIdx.x;
  const float* vrow = proj + ((size_t)b * NCH + ROW_V + v) * NPIX;
  uint* dst = vhg + (size_t)b * NCH * NPIX + (size_t)v * VH_WORDS;  // words == floats (4B)
  for (int p2 = t; p2 < 3784; p2 += 256) {
    int hr = p2 / 44;           // halo row 0..85
    int hc = (p2 % 44) * 2;     // halo col (even) 0..86
    int ir = hr - 11;
    int ic0 = hc - 11, ic1 = hc - 10;
    bool rok = (ir >= 0 && ir < 64);
    float f0 = (rok && ic0 >= 0 && ic0 < 64) ? vrow[ir * 64 + ic0] : 0.f;
    float f1 = (rok && ic1 >= 0 && ic1 < 64) ? vrow[ir * 64 + ic1] : 0.f;
    uint u0 = __float_as_uint(f0), u1 = __float_as_uint(f1);
    uint h0 = (u0 + 0x7fffu + ((u0 >> 16) & 1u)) >> 16;
    uint h1 = (u1 + 0x7fffu + ((u1 >> 16) & 1u)) >> 16;
    dst[p2] = (h0 & 0xffffu) | (h1 << 16);
  }
}

// ---------------- 4) lambda_c via MFMA, UNNORMALIZED exp + S accumulation ----------
// kf = x.Wk has sigma~0.8 (C=256, w~0.05): max|kf|<~4 -> exp<=~50, fp32-safe with
// no max subtraction. lcRaw[k][vv] = sum_n exp(kf[k][n]) v[vv][n]; S[k] = sum_n exp.
// Conv divides lcRaw/S (mathematically identical to softmax). Kills k_softstat.
__global__ __launch_bounds__(256) void k_lambda_c(
    const float* __restrict__ proj, float* __restrict__ lc, float* __restrict__ S) {
  int split = blockIdx.x;  // 0..63
  int b = blockIdx.y;
  int t = threadIdx.x;
  int lane = t & 63, w = t >> 6;
  int kr = lane & 15;       // A row (k); also B col (vv offset)
  int half = lane >> 4;     // k-dim offset 8*half
  const float* kfrow = proj + ((size_t)b * NCH + ROW_KF + kr) * NPIX;
  const float* vrow  = proj + ((size_t)b * NCH + ROW_V + w * 16 + kr) * NPIX;
  f32x4 acc = (f32x4)(0.f);
  float ssum = 0.f;
  #pragma unroll
  for (int c = 0; c < 2; c++) {
    int n0 = split * 64 + c * 32 + half * 8;
    float4 fa0 = *(const float4*)(kfrow + n0);
    float4 fa1 = *(const float4*)(kfrow + n0 + 4);
    float4 fb0 = *(const float4*)(vrow + n0);
    float4 fb1 = *(const float4*)(vrow + n0 + 4);
    float e0 = __expf(fa0.x), e1 = __expf(fa0.y), e2 = __expf(fa0.z), e3 = __expf(fa0.w);
    float e4 = __expf(fa1.x), e5 = __expf(fa1.y), e6 = __expf(fa1.z), e7 = __expf(fa1.w);
    ssum += (e0 + e1 + e2 + e3) + (e4 + e5 + e6 + e7);
    bf16x8 a, bb;
    a[0] = f2bf(e0); a[1] = f2bf(e1); a[2] = f2bf(e2); a[3] = f2bf(e3);
    a[4] = f2bf(e4); a[5] = f2bf(e5); a[6] = f2bf(e6); a[7] = f2bf(e7);
    bb[0] = f2bf(fb0.x); bb[1] = f2bf(fb0.y); bb[2] = f2bf(fb0.z); bb[3] = f2bf(fb0.w);
    bb[4] = f2bf(fb1.x); bb[5] = f2bf(fb1.y); bb[6] = f2bf(fb1.z); bb[7] = f2bf(fb1.w);
    acc = __builtin_amdgcn_mfma_f32_16x16x32_bf16(a, bb, acc, 0, 0, 0);
  }
  #pragma unroll
  for (int r = 0; r < 4; r++) {
    int k = half * 4 + r;
    atomicAdd(&lc[((size_t)b * 16 + k) * 64 + w * 16 + kr], acc[r]);
  }
  if (w == 0) {   // exp values identical across waves; only wave 0 contributes S
    ssum += __shfl_xor(ssum, 16);
    ssum += __shfl_xor(ssum, 32);
    if (lane < 16) atomicAdd(&S[b * 16 + kr], ssum);
  }
}

// ---------------- 5) MFMA implicit-im2col conv + fused epilogue ----------
// R4 wave structure (16-slot B-fragment ring, 1 new ds_read/dy). E now read
// DIRECTLY from global (etw: 23.5KB/variant, L1/L2-hot) instead of LDS-staged:
// LDS 38.9KB -> 15.1KB, occupancy 4 -> ~6-8 blocks/CU (latency fix without
// touching ring reuse; the R5/R6 failure mode does not apply). lc divided by S.
__global__ __launch_bounds__(256, 6) void k_conv_mfma(
    const float* __restrict__ proj, const ushort* __restrict__ etw,
    const float* __restrict__ qT, const float* __restrict__ lc,
    const float* __restrict__ S, const uint* __restrict__ vhg,
    float* __restrict__ outT, float* __restrict__ out, int mode) {
  int s = blockIdx.x;      // 0..7
  int v = blockIdx.y;      // 0..63
  int b = blockIdx.z;
  int t = threadIdx.x;
  __shared__ __align__(16) ushort vh[86 * 88];       // 15136 B halo bf16

  if (mode != 0) {
    const uint4* vsrc = (const uint4*)(vhg + (size_t)b * NCH * NPIX + (size_t)v * VH_WORDS);
    uint4* vdst = (uint4*)vh;
    for (int i = t; i < 946; i += 256) vdst[i] = vsrc[i];
  } else {
    const float* vrow = proj + ((size_t)b * NCH + ROW_V + v) * NPIX;
    for (int i = t; i < 86 * 88; i += 256) {
      int hr = i / 88, hc = i % 88;
      int ir = hr - 11, ic = hc - 11;
      float val = (ir >= 0 && ir < 64 && ic >= 0 && ic < 64) ? vrow[ir * 64 + ic] : 0.f;
      unsigned u = __float_as_uint(val);
      vh[i] = (ushort)((u + 0x7fffu + ((u >> 16) & 1u)) >> 16);
    }
  }
  __syncthreads();

  int lane = t & 63, w = t >> 6;
  int n_ = lane & 15, q = lane >> 4;
  int rn = n_ >> 3, g = n_ & 7;

  f32x4 acc[8];
  #pragma unroll
  for (int i = 0; i < 8; i++) acc[i] = (f32x4)(0.f);

  const bf16x8* vh8 = (const bf16x8*)vh;
  const bf16x8* e8 = (const bf16x8*)etw + (size_t)s * 1472;  // global, L1/L2-hot
  int baseA = (w * 16 + rn) * 11 + g + q;

  // prime circular fragment buffer with halo rows 0..15 (relative to baseA)
  bf16x8 bfr[16];
  #pragma unroll
  for (int r = 0; r < 16; r++)
    bfr[(r & 1) * 8 + ((r >> 1) & 7)] = vh8[baseA + r * 11];

  #pragma unroll
  for (int dy = 0; dy < 23; dy++) {
    bf16x8 ef = e8[dy * 64 + lane];
    // issue next row's read early; commit into the slot after this dy's MFMAs
    bf16x8 tmp;
    if (dy + 16 <= 36) tmp = vh8[baseA + (dy + 16) * 11];
    #pragma unroll
    for (int tt = 0; tt < 8; tt++) {
      int r = dy + 2 * tt;
      acc[tt] = __builtin_amdgcn_mfma_f32_16x16x32_bf16(
          ef, bfr[(r & 1) * 8 + ((r >> 1) & 7)], acc[tt], 0, 0, 0);
    }
    if (dy + 16 <= 36) {
      int rr = dy + 16;
      bfr[(rr & 1) * 8 + ((rr >> 1) & 7)] = tmp;
    }
  }

  float lcv[4];
  #pragma unroll
  for (int r = 0; r < 4; r++) {
    int k = q * 4 + r;
    lcv[r] = lc[((size_t)b * 16 + k) * 64 + v] / S[b * 16 + k];
  }

  if (mode != 0) {
    const float* qTb = qT + (size_t)b * 64 * NPIX;
    float* obT = outT + (size_t)b * 256 * NPIX;
    float* ob = out + (size_t)b * 256 * NPIX;
    #pragma unroll
    for (int tt = 0; tt < 8; tt++) {
      int row = w * 16 + 2 * tt + rn;
      int io = s * 512 + row * 8 + g;              // qT / outT index (coalesced)
      float lam[4];
      #pragma unroll
      for (int r = 0; r < 4; r++) lam[r] = acc[tt][r] + lcv[r];
      float y[4];
      #pragma unroll
      for (int h = 0; h < 4; h++) {
        float a = 0.f;
        #pragma unroll
        for (int r = 0; r < 4; r++)
          a += qTb[(size_t)(h * 16 + q * 4 + r) * NPIX + io] * lam[r];
        y[h] = a;
      }
      #pragma unroll
      for (int h = 0; h < 4; h++) {
        y[h] += __shfl_xor(y[h], 16);
        y[h] += __shfl_xor(y[h], 32);
      }
      if (q == 0) {
        if (mode == 2) {
          #pragma unroll
          for (int h = 0; h < 4; h++) obT[(size_t)(h * 64 + v) * NPIX + io] = y[h];
        } else {
          int p = row * 64 + 8 * g + s;
          #pragma unroll
          for (int h = 0; h < 4; h++) ob[(size_t)(h * 64 + v) * NPIX + p] = y[h];
        }
      }
    }
  } else {
    const float* qbp = proj + (size_t)b * NCH * NPIX;
    float* ob = out + (size_t)b * 256 * NPIX;
    #pragma unroll
    for (int tt = 0; tt < 8; tt++) {
      int p = (w * 16 + 2 * tt + rn) * 64 + 8 * g + s;
      float lam[4];
      #pragma unroll
      for (int r = 0; r < 4; r++) lam[r] = acc[tt][r] + lcv[r];
      float y[4];
      #pragma unroll
      for (int h = 0; h < 4; h++) {
        float a = 0.f;
        #pragma unroll
        for (int r = 0; r < 4; r++)
          a += qbp[(size_t)(h * 16 + q * 4 + r) * NPIX + p] * lam[r];
        y[h] = a;
      }
      #pragma unroll
      for (int h = 0; h < 4; h++) {
        y[h] += __shfl_xor(y[h], 16);
        y[h] += __shfl_xor(y[h], 32);
      }
      if (q == 0) {
        #pragma unroll
        for (int h = 0; h < 4; h++) ob[(size_t)(h * 64 + v) * NPIX + p] = y[h];
      }
    }
  }
}

// ---------------- 6) un-transpose: outT[b][ch][s*512+i] -> out[b][ch][p] ----------
__global__ __launch_bounds__(256) void k_outtrans(
    const float* __restrict__ outT, float* __restrict__ out) {
  int ch = blockIdx.x, b = blockIdx.y, t = threadIdx.x;
  __shared__ float buf[4608];
  const float* src = outT + ((size_t)b * 256 + ch) * NPIX;
  for (int it = 0; it < 16; it++) {
    int idx = it * 256 + t;           // s*512 + i
    int s = idx >> 9, i = idx & 511;
    int p = (i >> 3) * 64 + (i & 7) * 8 + s;
    buf[p + (p >> 3)] = src[idx];
  }
  __syncthreads();
  float* dst = out + ((size_t)b * 256 + ch) * NPIX;
  for (int it = 0; it < 16; it++) {
    int p = it * 256 + t;
    dst[p] = buf[p + (p >> 3)];
  }
}

extern "C" void kernel_launch(void* const* d_in, const int* in_sizes, int n_in,
                              void* d_out, int out_size, void* d_ws, size_t ws_size,
                              hipStream_t stream) {
  const float* x    = (const float*)d_in[0];
  const float* Wq   = (const float*)d_in[1];
  const float* qg   = (const float*)d_in[2];
  const float* qbta = (const float*)d_in[3];
  const float* qm   = (const float*)d_in[4];
  const float* qv   = (const float*)d_in[5];
  const float* Wk   = (const float*)d_in[6];
  const float* Wv   = (const float*)d_in[7];
  const float* vg   = (const float*)d_in[8];
  const float* vb   = (const float*)d_in[9];
  const float* vm   = (const float*)d_in[10];
  const float* vvar = (const float*)d_in[11];
  const float* emb  = (const float*)d_in[12];
  float* ws   = (float*)d_ws;
  float* Wt   = ws + WP_OFF;
  float* bp   = ws + BIAS_OFF;
  float* proj = ws + PROJ_OFF;
  float* Sw   = ws + RMAX_OFF;
  float* lcw  = ws + LC_OFF;
  ushort* etw = (ushort*)(ws + ET_OFF);
  float* qT   = ws + QT_OFF;
  float* outT = ws + OUTT_OFF;
  float* out  = (float*)d_out;
  uint* vhg   = (uint*)proj;      // dead q-row region of proj, reused per (b,v)
  ushort* wtA = (ushort*)qT;      // qT region head; consumed before k_qtrans writes

  size_t wsf = ws_size / sizeof(float);
  int mode = (wsf >= WS_NEED_FULL) ? 2 : ((wsf >= WS_NEED_QT) ? 1 : 0);

  hipLaunchKernelGGL(k_prep, dim3(512), dim3(256), 0, stream,
                     Wq, qg, qbta, qm, qv, Wk, Wv, vg, vb, vm, vvar, emb, Wt, bp, etw);
  hipMemsetAsync(Sw, 0, 8448 * sizeof(float), stream);   // S (256) + lc (8192)
  if (mode >= 1) {
    hipLaunchKernelGGL(k_wprep, dim3(18), dim3(256), 0, stream, Wt, wtA);
    hipLaunchKernelGGL(k_projm, dim3(64, 8), dim3(256), 0, stream, x, wtA, bp, proj);
    hipLaunchKernelGGL(k_qtrans, dim3(64, 8), dim3(256), 0, stream, proj, qT);
    hipLaunchKernelGGL(k_vhalo, dim3(64, 8), dim3(256), 0, stream, proj, vhg);
  } else {
    hipLaunchKernelGGL(k_proj, dim3(16, 8, 8), dim3(256), 0, stream, x, Wt, bp, proj);
  }
  hipLaunchKernelGGL(k_lambda_c, dim3(64, 8), dim3(256), 0, stream, proj, lcw, Sw);
  hipLaunchKernelGGL(k_conv_mfma, dim3(8, 64, 8), dim3(256), 0, stream,
                     proj, etw, qT, lcw, Sw, vhg, outT, out, mode);
  if (mode == 2)
    hipLaunchKernelGGL(k_outtrans, dim3(256, 8), dim3(256), 0, stream, outT, out);
}

// Round 11
// 220.032 us; speedup vs baseline: 2.5420x; 2.5420x over previous
//
#include <hip/hip_runtime.h>

typedef __attribute__((ext_vector_type(8))) short bf16x8;
typedef __attribute__((ext_vector_type(4))) float f32x4;

#define EPS 1e-5f
#define B 8
#define C 256
#define NPIX 4096      // 64*64
#define NCH 144        // rows: 0..63 q_bn, 64..127 v_bn, 128..143 kf(raw)
#define ROW_V 64
#define ROW_KF 128
#define PAD 11
#define VH_WORDS 3840  // 4-byte words reserved per (v,b) halo (3784 used)

// workspace layout (float offsets)
#define WP_OFF    0u          // Wt transposed: 256*144 = 36864
#define BIAS_OFF  36864u      // 144
#define PROJ_OFF  37120u      // 8*144*4096 = 4718592
#define RMAX_OFF  4755712u    // now S: 128 softmax denominators (+128 pad)
#define LC_OFF    4755968u    // 8*16*64 = 8192 (raw, divided by S in conv)
#define ET_OFF    4764160u    // E variants: 94208 ushort = 47104 floats
#define QT_OFF    4811264u    // qT: 8*64*4096 = 2097152 (wtA borrows its head pre-qtrans)
#define OUTT_OFF  6908416u    // outT: 8*256*4096 = 8388608 (end 15297024 floats)
#define WS_NEED_QT    6908416u
#define WS_NEED_FULL  15297024u

__device__ inline short f2bf(float f) {
  unsigned u = __float_as_uint(f);
  return (short)((u + 0x7fffu + ((u >> 16) & 1u)) >> 16);
}

// ---------------- 1) fused prep: blocks 0..143 fold BN into Wt; 144..511 build E ----
__global__ __launch_bounds__(256) void k_prep(
    const float* __restrict__ Wq, const float* __restrict__ qg, const float* __restrict__ qb,
    const float* __restrict__ qm, const float* __restrict__ qv,
    const float* __restrict__ Wk, const float* __restrict__ Wv,
    const float* __restrict__ vg, const float* __restrict__ vb,
    const float* __restrict__ vm, const float* __restrict__ vvar,
    const float* __restrict__ emb,
    float* __restrict__ Wt, float* __restrict__ biasp, ushort* __restrict__ etw) {
  int t = threadIdx.x;
  if (blockIdx.x < 144) {
    int o = blockIdx.x;   // 0..143
    const float* src; float s, bias;
    if (o < 64) {
      s = qg[o] * rsqrtf(qv[o] + EPS); bias = qb[o] - qm[o] * s; src = Wq + o * C;
    } else if (o < 128) {
      int i = o - 64;
      s = vg[i] * rsqrtf(vvar[i] + EPS); bias = vb[i] - vm[i] * s; src = Wv + i * C;
    } else {
      int i = o - 128; s = 1.f; bias = 0.f; src = Wk + i * C;
    }
    Wt[t * NCH + o] = src[t] * s;
    if (t == 0) biasp[o] = bias;
  } else {
    int i = (blockIdx.x - 144) * 256 + t;   // 0..94207
    int s = i / 11776;
    int r = i % 11776;
    int dy = r / 512;
    int l = (r / 8) % 64;
    int jj = r % 8;
    int f = l & 15, q = l >> 4;
    int dx = q * 8 + jj - s;
    float val = (dx >= 0 && dx < 23) ? emb[f * 529 + dy * 23 + dx] : 0.f;
    unsigned u = __float_as_uint(val);
    etw[i] = (ushort)((u + 0x7fffu + ((u >> 16) & 1u)) >> 16);
  }
}

// ---------------- 1c) prepack Wt into MFMA A-fragment order (bf16) ----------------
__global__ __launch_bounds__(256) void k_wprep(
    const float* __restrict__ Wt, ushort* __restrict__ wtA) {
  int i = blockIdx.x * 256 + threadIdx.x;   // 0..4607
  int mt = i >> 9;
  int rest = i & 511;
  int kt = rest >> 6;
  int lane = rest & 63;
  int m = mt * 16 + (lane & 15);
  int c0 = kt * 32 + (lane >> 4) * 8;
  ushort* dst = wtA + (size_t)i * 8;
  #pragma unroll
  for (int j = 0; j < 8; j++) {
    float v = Wt[(c0 + j) * NCH + m];
    unsigned u = __float_as_uint(v);
    dst[j] = (ushort)((u + 0x7fffu + ((u >> 16) & 1u)) >> 16);
  }
}

// ---------------- 2) projection as MFMA GEMM: proj = Wt^T x + bias ----------------
__global__ __launch_bounds__(256) void k_projm(
    const float* __restrict__ x, const ushort* __restrict__ wtA,
    const float* __restrict__ biasp, float* __restrict__ proj) {
  int ntile = blockIdx.x;  // 0..63
  int b = blockIdx.y;
  int t = threadIdx.x;
  int lane = t & 63, w = t >> 6;
  int px = ntile * 64 + w * 16 + (lane & 15);
  int kq = lane >> 4;
  const float* xb = x + (size_t)b * C * NPIX + px;
  const bf16x8* A = (const bf16x8*)wtA;
  f32x4 acc[9];
  #pragma unroll
  for (int i = 0; i < 9; i++) acc[i] = (f32x4)(0.f);
  #pragma unroll 2
  for (int kt = 0; kt < 8; kt++) {
    int c0 = kt * 32 + kq * 8;
    bf16x8 bb;
    #pragma unroll
    for (int j = 0; j < 8; j++) bb[j] = f2bf(xb[(size_t)(c0 + j) * NPIX]);
    #pragma unroll
    for (int mt = 0; mt < 9; mt++) {
      bf16x8 a = A[(mt * 8 + kt) * 64 + lane];
      acc[mt] = __builtin_amdgcn_mfma_f32_16x16x32_bf16(a, bb, acc[mt], 0, 0, 0);
    }
  }
  float* pb = proj + (size_t)b * NCH * NPIX + px;
  #pragma unroll
  for (int mt = 0; mt < 9; mt++) {
    #pragma unroll
    for (int r = 0; r < 4; r++) {
      int ch = mt * 16 + kq * 4 + r;
      pb[(size_t)ch * NPIX] = acc[mt][r] + biasp[ch];
    }
  }
}

// ---------------- 2-fallback) VALU projection (mode 0 only) ----------
__global__ __launch_bounds__(256) void k_proj(
    const float* __restrict__ x, const float* __restrict__ Wt,
    const float* __restrict__ biasp, float* __restrict__ proj) {
  int tile = blockIdx.x;  // 0..15
  int g = blockIdx.y;     // 0..7 (18 ch each)
  int b = blockIdx.z;
  int t = threadIdx.x;
  int px = tile * 256 + t;
  const float* xb = x + (size_t)b * C * NPIX + px;
  float acc[18];
  #pragma unroll
  for (int i = 0; i < 18; i++) acc[i] = 0.f;
  #pragma unroll 4
  for (int c = 0; c < C; c++) {
    float xv = xb[(size_t)c * NPIX];
    const float* wrow = Wt + c * NCH + g * 18;   // uniform -> s_load
    #pragma unroll
    for (int i = 0; i < 18; i++) acc[i] += xv * wrow[i];
  }
  float* ob = proj + ((size_t)b * NCH + g * 18) * NPIX + px;
  #pragma unroll
  for (int i = 0; i < 18; i++) ob[(size_t)i * NPIX] = acc[i] + biasp[g * 18 + i];
}

// ---------------- 2b) transpose q rows: proj[b][ch][p] -> qT[b][ch][s*512+i] ----------
__global__ __launch_bounds__(256) void k_qtrans(
    const float* __restrict__ proj, float* __restrict__ qT) {
  int ch = blockIdx.x, b = blockIdx.y, t = threadIdx.x;
  __shared__ float buf[4608];
  const float* src = proj + ((size_t)b * NCH + ch) * NPIX;
  for (int it = 0; it < 16; it++) {
    int p = it * 256 + t;
    buf[p + (p >> 3)] = src[p];
  }
  __syncthreads();
  float* dst = qT + ((size_t)b * 64 + ch) * NPIX;
  for (int it = 0; it < 16; it++) {
    int idx = it * 256 + t;           // s*512 + i
    int s = idx >> 9, i = idx & 511;
    int p = (i >> 3) * 64 + (i & 7) * 8 + s;
    dst[idx] = buf[p + (p >> 3)];
  }
}

// ---------------- 2c) prebuild bf16 halos: one 86x88 halo per (v,b) ----------------
__global__ __launch_bounds__(256) void k_vhalo(
    const float* __restrict__ proj, uint* __restrict__ vhg) {
  int v = blockIdx.x, b = blockIdx.y, t = threadIdx.x;
  const float* vrow = proj + ((size_t)b * NCH + ROW_V + v) * NPIX;
  uint* dst = vhg + (size_t)b * NCH * NPIX + (size_t)v * VH_WORDS;  // words == floats (4B)
  for (int p2 = t; p2 < 3784; p2 += 256) {
    int hr = p2 / 44;           // halo row 0..85
    int hc = (p2 % 44) * 2;     // halo col (even) 0..86
    int ir = hr - 11;
    int ic0 = hc - 11, ic1 = hc - 10;
    bool rok = (ir >= 0 && ir < 64);
    float f0 = (rok && ic0 >= 0 && ic0 < 64) ? vrow[ir * 64 + ic0] : 0.f;
    float f1 = (rok && ic1 >= 0 && ic1 < 64) ? vrow[ir * 64 + ic1] : 0.f;
    uint u0 = __float_as_uint(f0), u1 = __float_as_uint(f1);
    uint h0 = (u0 + 0x7fffu + ((u0 >> 16) & 1u)) >> 16;
    uint h1 = (u1 + 0x7fffu + ((u1 >> 16) & 1u)) >> 16;
    dst[p2] = (h0 & 0xffffu) | (h1 << 16);
  }
}

// ---------------- 4) lambda_c via MFMA, UNNORMALIZED exp + S accumulation ----------
// kf sigma~0.8 -> exp<=~50, fp32-safe without max subtraction (validated R10:
// passed with absmax unchanged). Conv divides lcRaw/S. k_softstat eliminated.
__global__ __launch_bounds__(256) void k_lambda_c(
    const float* __restrict__ proj, float* __restrict__ lc, float* __restrict__ S) {
  int split = blockIdx.x;  // 0..63
  int b = blockIdx.y;
  int t = threadIdx.x;
  int lane = t & 63, w = t >> 6;
  int kr = lane & 15;       // A row (k); also B col (vv offset)
  int half = lane >> 4;     // k-dim offset 8*half
  const float* kfrow = proj + ((size_t)b * NCH + ROW_KF + kr) * NPIX;
  const float* vrow  = proj + ((size_t)b * NCH + ROW_V + w * 16 + kr) * NPIX;
  f32x4 acc = (f32x4)(0.f);
  float ssum = 0.f;
  #pragma unroll
  for (int c = 0; c < 2; c++) {
    int n0 = split * 64 + c * 32 + half * 8;
    float4 fa0 = *(const float4*)(kfrow + n0);
    float4 fa1 = *(const float4*)(kfrow + n0 + 4);
    float4 fb0 = *(const float4*)(vrow + n0);
    float4 fb1 = *(const float4*)(vrow + n0 + 4);
    float e0 = __expf(fa0.x), e1 = __expf(fa0.y), e2 = __expf(fa0.z), e3 = __expf(fa0.w);
    float e4 = __expf(fa1.x), e5 = __expf(fa1.y), e6 = __expf(fa1.z), e7 = __expf(fa1.w);
    ssum += (e0 + e1 + e2 + e3) + (e4 + e5 + e6 + e7);
    bf16x8 a, bb;
    a[0] = f2bf(e0); a[1] = f2bf(e1); a[2] = f2bf(e2); a[3] = f2bf(e3);
    a[4] = f2bf(e4); a[5] = f2bf(e5); a[6] = f2bf(e6); a[7] = f2bf(e7);
    bb[0] = f2bf(fb0.x); bb[1] = f2bf(fb0.y); bb[2] = f2bf(fb0.z); bb[3] = f2bf(fb0.w);
    bb[4] = f2bf(fb1.x); bb[5] = f2bf(fb1.y); bb[6] = f2bf(fb1.z); bb[7] = f2bf(fb1.w);
    acc = __builtin_amdgcn_mfma_f32_16x16x32_bf16(a, bb, acc, 0, 0, 0);
  }
  #pragma unroll
  for (int r = 0; r < 4; r++) {
    int k = half * 4 + r;
    atomicAdd(&lc[((size_t)b * 16 + k) * 64 + w * 16 + kr], acc[r]);
  }
  if (w == 0) {   // exp values identical across waves; only wave 0 contributes S
    ssum += __shfl_xor(ssum, 16);
    ssum += __shfl_xor(ssum, 32);
    if (lane < 16) atomicAdd(&S[b * 16 + kr], ssum);
  }
}

// ---------------- 5) MFMA implicit-im2col conv + fused epilogue (R4/R9 winner) -----
// LDS-staged E + 16-slot B-fragment ring + launch_bounds(256,2). DO NOT touch
// occupancy levers here: R5 (512thr) and R10 (bounds(256,6), E-from-global)
// both spilled the ~100-VGPR live state -> 1.6GB scratch traffic. Only delta
// vs R9: lcv = lc/S (unnormalized-softmax epilogue).
__global__ __launch_bounds__(256, 2) void k_conv_mfma(
    const float* __restrict__ proj, const ushort* __restrict__ etw,
    const float* __restrict__ qT, const float* __restrict__ lc,
    const float* __restrict__ S, const uint* __restrict__ vhg,
    float* __restrict__ outT, float* __restrict__ out, int mode) {
  int s = blockIdx.x;      // 0..7
  int v = blockIdx.y;      // 0..63
  int b = blockIdx.z;
  int t = threadIdx.x;
  __shared__ __align__(16) ushort vh[86 * 88];       // 15136 B halo bf16
  __shared__ __align__(16) ushort elds[23 * 64 * 8]; // 23552 B E_s chunks

  {
    const uint4* src = (const uint4*)etw + s * 1472;
    uint4* dst = (uint4*)elds;
    for (int i = t; i < 1472; i += 256) dst[i] = src[i];
  }
  if (mode != 0) {
    const uint4* vsrc = (const uint4*)(vhg + (size_t)b * NCH * NPIX + (size_t)v * VH_WORDS);
    uint4* vdst = (uint4*)vh;
    for (int i = t; i < 946; i += 256) vdst[i] = vsrc[i];
  } else {
    const float* vrow = proj + ((size_t)b * NCH + ROW_V + v) * NPIX;
    for (int i = t; i < 86 * 88; i += 256) {
      int hr = i / 88, hc = i % 88;
      int ir = hr - 11, ic = hc - 11;
      float val = (ir >= 0 && ir < 64 && ic >= 0 && ic < 64) ? vrow[ir * 64 + ic] : 0.f;
      unsigned u = __float_as_uint(val);
      vh[i] = (ushort)((u + 0x7fffu + ((u >> 16) & 1u)) >> 16);
    }
  }
  __syncthreads();

  int lane = t & 63, w = t >> 6;
  int n_ = lane & 15, q = lane >> 4;
  int rn = n_ >> 3, g = n_ & 7;

  f32x4 acc[8];
  #pragma unroll
  for (int i = 0; i < 8; i++) acc[i] = (f32x4)(0.f);

  const bf16x8* vh8 = (const bf16x8*)vh;
  const bf16x8* e8 = (const bf16x8*)elds;
  int baseA = (w * 16 + rn) * 11 + g + q;

  // prime circular fragment buffer with halo rows 0..15 (relative to baseA)
  bf16x8 bfr[16];
  #pragma unroll
  for (int r = 0; r < 16; r++)
    bfr[(r & 1) * 8 + ((r >> 1) & 7)] = vh8[baseA + r * 11];

  #pragma unroll
  for (int dy = 0; dy < 23; dy++) {
    bf16x8 ef = e8[dy * 64 + lane];
    // issue next row's read early; commit into the slot after this dy's MFMAs
    bf16x8 tmp;
    if (dy + 16 <= 36) tmp = vh8[baseA + (dy + 16) * 11];
    #pragma unroll
    for (int tt = 0; tt < 8; tt++) {
      int r = dy + 2 * tt;
      acc[tt] = __builtin_amdgcn_mfma_f32_16x16x32_bf16(
          ef, bfr[(r & 1) * 8 + ((r >> 1) & 7)], acc[tt], 0, 0, 0);
    }
    if (dy + 16 <= 36) {
      int rr = dy + 16;
      bfr[(rr & 1) * 8 + ((rr >> 1) & 7)] = tmp;
    }
  }

  float lcv[4];
  #pragma unroll
  for (int r = 0; r < 4; r++) {
    int k = q * 4 + r;
    lcv[r] = lc[((size_t)b * 16 + k) * 64 + v] / S[b * 16 + k];
  }

  if (mode != 0) {
    const float* qTb = qT + (size_t)b * 64 * NPIX;
    float* obT = outT + (size_t)b * 256 * NPIX;
    float* ob = out + (size_t)b * 256 * NPIX;
    #pragma unroll
    for (int tt = 0; tt < 8; tt++) {
      int row = w * 16 + 2 * tt + rn;
      int io = s * 512 + row * 8 + g;              // qT / outT index (coalesced)
      float lam[4];
      #pragma unroll
      for (int r = 0; r < 4; r++) lam[r] = acc[tt][r] + lcv[r];
      float y[4];
      #pragma unroll
      for (int h = 0; h < 4; h++) {
        float a = 0.f;
        #pragma unroll
        for (int r = 0; r < 4; r++)
          a += qTb[(size_t)(h * 16 + q * 4 + r) * NPIX + io] * lam[r];
        y[h] = a;
      }
      #pragma unroll
      for (int h = 0; h < 4; h++) {
        y[h] += __shfl_xor(y[h], 16);
        y[h] += __shfl_xor(y[h], 32);
      }
      if (q == 0) {
        if (mode == 2) {
          #pragma unroll
          for (int h = 0; h < 4; h++) obT[(size_t)(h * 64 + v) * NPIX + io] = y[h];
        } else {
          int p = row * 64 + 8 * g + s;
          #pragma unroll
          for (int h = 0; h < 4; h++) ob[(size_t)(h * 64 + v) * NPIX + p] = y[h];
        }
      }
    }
  } else {
    const float* qbp = proj + (size_t)b * NCH * NPIX;
    float* ob = out + (size_t)b * 256 * NPIX;
    #pragma unroll
    for (int tt = 0; tt < 8; tt++) {
      int p = (w * 16 + 2 * tt + rn) * 64 + 8 * g + s;
      float lam[4];
      #pragma unroll
      for (int r = 0; r < 4; r++) lam[r] = acc[tt][r] + lcv[r];
      float y[4];
      #pragma unroll
      for (int h = 0; h < 4; h++) {
        float a = 0.f;
        #pragma unroll
        for (int r = 0; r < 4; r++)
          a += qbp[(size_t)(h * 16 + q * 4 + r) * NPIX + p] * lam[r];
        y[h] = a;
      }
      #pragma unroll
      for (int h = 0; h < 4; h++) {
        y[h] += __shfl_xor(y[h], 16);
        y[h] += __shfl_xor(y[h], 32);
      }
      if (q == 0) {
        #pragma unroll
        for (int h = 0; h < 4; h++) ob[(size_t)(h * 64 + v) * NPIX + p] = y[h];
      }
    }
  }
}

// ---------------- 6) un-transpose: outT[b][ch][s*512+i] -> out[b][ch][p] ----------
__global__ __launch_bounds__(256) void k_outtrans(
    const float* __restrict__ outT, float* __restrict__ out) {
  int ch = blockIdx.x, b = blockIdx.y, t = threadIdx.x;
  __shared__ float buf[4608];
  const float* src = outT + ((size_t)b * 256 + ch) * NPIX;
  for (int it = 0; it < 16; it++) {
    int idx = it * 256 + t;           // s*512 + i
    int s = idx >> 9, i = idx & 511;
    int p = (i >> 3) * 64 + (i & 7) * 8 + s;
    buf[p + (p >> 3)] = src[idx];
  }
  __syncthreads();
  float* dst = out + ((size_t)b * 256 + ch) * NPIX;
  for (int it = 0; it < 16; it++) {
    int p = it * 256 + t;
    dst[p] = buf[p + (p >> 3)];
  }
}

extern "C" void kernel_launch(void* const* d_in, const int* in_sizes, int n_in,
                              void* d_out, int out_size, void* d_ws, size_t ws_size,
                              hipStream_t stream) {
  const float* x    = (const float*)d_in[0];
  const float* Wq   = (const float*)d_in[1];
  const float* qg   = (const float*)d_in[2];
  const float* qbta = (const float*)d_in[3];
  const float* qm   = (const float*)d_in[4];
  const float* qv   = (const float*)d_in[5];
  const float* Wk   = (const float*)d_in[6];
  const float* Wv   = (const float*)d_in[7];
  const float* vg   = (const float*)d_in[8];
  const float* vb   = (const float*)d_in[9];
  const float* vm   = (const float*)d_in[10];
  const float* vvar = (const float*)d_in[11];
  const float* emb  = (const float*)d_in[12];
  float* ws   = (float*)d_ws;
  float* Wt   = ws + WP_OFF;
  float* bp   = ws + BIAS_OFF;
  float* proj = ws + PROJ_OFF;
  float* Sw   = ws + RMAX_OFF;
  float* lcw  = ws + LC_OFF;
  ushort* etw = (ushort*)(ws + ET_OFF);
  float* qT   = ws + QT_OFF;
  float* outT = ws + OUTT_OFF;
  float* out  = (float*)d_out;
  uint* vhg   = (uint*)proj;      // dead q-row region of proj, reused per (b,v)
  ushort* wtA = (ushort*)qT;      // qT region head; consumed before k_qtrans writes

  size_t wsf = ws_size / sizeof(float);
  int mode = (wsf >= WS_NEED_FULL) ? 2 : ((wsf >= WS_NEED_QT) ? 1 : 0);

  hipLaunchKernelGGL(k_prep, dim3(512), dim3(256), 0, stream,
                     Wq, qg, qbta, qm, qv, Wk, Wv, vg, vb, vm, vvar, emb, Wt, bp, etw);
  hipMemsetAsync(Sw, 0, 8448 * sizeof(float), stream);   // S (256) + lc (8192)
  if (mode >= 1) {
    hipLaunchKernelGGL(k_wprep, dim3(18), dim3(256), 0, stream, Wt, wtA);
    hipLaunchKernelGGL(k_projm, dim3(64, 8), dim3(256), 0, stream, x, wtA, bp, proj);
    hipLaunchKernelGGL(k_qtrans, dim3(64, 8), dim3(256), 0, stream, proj, qT);
    hipLaunchKernelGGL(k_vhalo, dim3(64, 8), dim3(256), 0, stream, proj, vhg);
  } else {
    hipLaunchKernelGGL(k_proj, dim3(16, 8, 8), dim3(256), 0, stream, x, Wt, bp, proj);
  }
  hipLaunchKernelGGL(k_lambda_c, dim3(64, 8), dim3(256), 0, stream, proj, lcw, Sw);
  hipLaunchKernelGGL(k_conv_mfma, dim3(8, 64, 8), dim3(256), 0, stream,
                     proj, etw, qT, lcw, Sw, vhg, outT, out, mode);
  if (mode == 2)
    hipLaunchKernelGGL(k_outtrans, dim3(256, 8), dim3(256), 0, stream, outT, out);
}

// Round 12
// 214.020 us; speedup vs baseline: 2.6134x; 1.0281x over previous
//
#include <hip/hip_runtime.h>

typedef __attribute__((ext_vector_type(8))) short bf16x8;
typedef __attribute__((ext_vector_type(4))) float f32x4;

#define EPS 1e-5f
#define B 8
#define C 256
#define NPIX 4096      // 64*64
#define NCH 144        // rows: 0..63 q_bn, 64..127 v_bn, 128..143 kf(raw)
#define ROW_V 64
#define ROW_KF 128
#define PAD 11
#define VH_WORDS 3840  // 4-byte words reserved per (v,b) halo (3784 used)

// workspace layout (float offsets)
#define WP_OFF    0u          // Wt transposed: 256*144 = 36864
#define BIAS_OFF  36864u      // 144
#define PROJ_OFF  37120u      // 8*144*4096 = 4718592
#define RMAX_OFF  4755712u    // now S: 128 softmax denominators (+128 pad)
#define LC_OFF    4755968u    // 8*16*64 = 8192 (raw, normalized by k_lcnorm)
#define ET_OFF    4764160u    // E variants: 94208 ushort = 47104 floats
#define QT_OFF    4811264u    // qT: 8*64*4096 = 2097152 (wtA borrows its head pre-qtrans)
#define OUTT_OFF  6908416u    // outT: 8*256*4096 = 8388608 (end 15297024 floats)
#define WS_NEED_QT    6908416u
#define WS_NEED_FULL  15297024u

__device__ inline short f2bf(float f) {
  unsigned u = __float_as_uint(f);
  return (short)((u + 0x7fffu + ((u >> 16) & 1u)) >> 16);
}

// ---------------- 1) fused prep: blocks 0..143 fold BN into Wt; 144..511 build E ----
__global__ __launch_bounds__(256) void k_prep(
    const float* __restrict__ Wq, const float* __restrict__ qg, const float* __restrict__ qb,
    const float* __restrict__ qm, const float* __restrict__ qv,
    const float* __restrict__ Wk, const float* __restrict__ Wv,
    const float* __restrict__ vg, const float* __restrict__ vb,
    const float* __restrict__ vm, const float* __restrict__ vvar,
    const float* __restrict__ emb,
    float* __restrict__ Wt, float* __restrict__ biasp, ushort* __restrict__ etw) {
  int t = threadIdx.x;
  if (blockIdx.x < 144) {
    int o = blockIdx.x;   // 0..143
    const float* src; float s, bias;
    if (o < 64) {
      s = qg[o] * rsqrtf(qv[o] + EPS); bias = qb[o] - qm[o] * s; src = Wq + o * C;
    } else if (o < 128) {
      int i = o - 64;
      s = vg[i] * rsqrtf(vvar[i] + EPS); bias = vb[i] - vm[i] * s; src = Wv + i * C;
    } else {
      int i = o - 128; s = 1.f; bias = 0.f; src = Wk + i * C;
    }
    Wt[t * NCH + o] = src[t] * s;
    if (t == 0) biasp[o] = bias;
  } else {
    int i = (blockIdx.x - 144) * 256 + t;   // 0..94207
    int s = i / 11776;
    int r = i % 11776;
    int dy = r / 512;
    int l = (r / 8) % 64;
    int jj = r % 8;
    int f = l & 15, q = l >> 4;
    int dx = q * 8 + jj - s;
    float val = (dx >= 0 && dx < 23) ? emb[f * 529 + dy * 23 + dx] : 0.f;
    unsigned u = __float_as_uint(val);
    etw[i] = (ushort)((u + 0x7fffu + ((u >> 16) & 1u)) >> 16);
  }
}

// ---------------- 1c) prepack Wt into MFMA A-fragment order (bf16) ----------------
__global__ __launch_bounds__(256) void k_wprep(
    const float* __restrict__ Wt, ushort* __restrict__ wtA) {
  int i = blockIdx.x * 256 + threadIdx.x;   // 0..4607
  int mt = i >> 9;
  int rest = i & 511;
  int kt = rest >> 6;
  int lane = rest & 63;
  int m = mt * 16 + (lane & 15);
  int c0 = kt * 32 + (lane >> 4) * 8;
  ushort* dst = wtA + (size_t)i * 8;
  #pragma unroll
  for (int j = 0; j < 8; j++) {
    float v = Wt[(c0 + j) * NCH + m];
    unsigned u = __float_as_uint(v);
    dst[j] = (ushort)((u + 0x7fffu + ((u >> 16) & 1u)) >> 16);
  }
}

// ---------------- 2) projection as MFMA GEMM: proj = Wt^T x + bias ----------------
__global__ __launch_bounds__(256) void k_projm(
    const float* __restrict__ x, const ushort* __restrict__ wtA,
    const float* __restrict__ biasp, float* __restrict__ proj) {
  int ntile = blockIdx.x;  // 0..63
  int b = blockIdx.y;
  int t = threadIdx.x;
  int lane = t & 63, w = t >> 6;
  int px = ntile * 64 + w * 16 + (lane & 15);
  int kq = lane >> 4;
  const float* xb = x + (size_t)b * C * NPIX + px;
  const bf16x8* A = (const bf16x8*)wtA;
  f32x4 acc[9];
  #pragma unroll
  for (int i = 0; i < 9; i++) acc[i] = (f32x4)(0.f);
  #pragma unroll 2
  for (int kt = 0; kt < 8; kt++) {
    int c0 = kt * 32 + kq * 8;
    bf16x8 bb;
    #pragma unroll
    for (int j = 0; j < 8; j++) bb[j] = f2bf(xb[(size_t)(c0 + j) * NPIX]);
    #pragma unroll
    for (int mt = 0; mt < 9; mt++) {
      bf16x8 a = A[(mt * 8 + kt) * 64 + lane];
      acc[mt] = __builtin_amdgcn_mfma_f32_16x16x32_bf16(a, bb, acc[mt], 0, 0, 0);
    }
  }
  float* pb = proj + (size_t)b * NCH * NPIX + px;
  #pragma unroll
  for (int mt = 0; mt < 9; mt++) {
    #pragma unroll
    for (int r = 0; r < 4; r++) {
      int ch = mt * 16 + kq * 4 + r;
      pb[(size_t)ch * NPIX] = acc[mt][r] + biasp[ch];
    }
  }
}

// ---------------- 2-fallback) VALU projection (mode 0 only) ----------
__global__ __launch_bounds__(256) void k_proj(
    const float* __restrict__ x, const float* __restrict__ Wt,
    const float* __restrict__ biasp, float* __restrict__ proj) {
  int tile = blockIdx.x;  // 0..15
  int g = blockIdx.y;     // 0..7 (18 ch each)
  int b = blockIdx.z;
  int t = threadIdx.x;
  int px = tile * 256 + t;
  const float* xb = x + (size_t)b * C * NPIX + px;
  float acc[18];
  #pragma unroll
  for (int i = 0; i < 18; i++) acc[i] = 0.f;
  #pragma unroll 4
  for (int c = 0; c < C; c++) {
    float xv = xb[(size_t)c * NPIX];
    const float* wrow = Wt + c * NCH + g * 18;   // uniform -> s_load
    #pragma unroll
    for (int i = 0; i < 18; i++) acc[i] += xv * wrow[i];
  }
  float* ob = proj + ((size_t)b * NCH + g * 18) * NPIX + px;
  #pragma unroll
  for (int i = 0; i < 18; i++) ob[(size_t)i * NPIX] = acc[i] + biasp[g * 18 + i];
}

// ---------------- 2b) transpose q rows: proj[b][ch][p] -> qT[b][ch][s*512+i] ----------
__global__ __launch_bounds__(256) void k_qtrans(
    const float* __restrict__ proj, float* __restrict__ qT) {
  int ch = blockIdx.x, b = blockIdx.y, t = threadIdx.x;
  __shared__ float buf[4608];
  const float* src = proj + ((size_t)b * NCH + ch) * NPIX;
  for (int it = 0; it < 16; it++) {
    int p = it * 256 + t;
    buf[p + (p >> 3)] = src[p];
  }
  __syncthreads();
  float* dst = qT + ((size_t)b * 64 + ch) * NPIX;
  for (int it = 0; it < 16; it++) {
    int idx = it * 256 + t;           // s*512 + i
    int s = idx >> 9, i = idx & 511;
    int p = (i >> 3) * 64 + (i & 7) * 8 + s;
    dst[idx] = buf[p + (p >> 3)];
  }
}

// ---------------- 2c) prebuild bf16 halos: one 86x88 halo per (v,b) ----------------
__global__ __launch_bounds__(256) void k_vhalo(
    const float* __restrict__ proj, uint* __restrict__ vhg) {
  int v = blockIdx.x, b = blockIdx.y, t = threadIdx.x;
  const float* vrow = proj + ((size_t)b * NCH + ROW_V + v) * NPIX;
  uint* dst = vhg + (size_t)b * NCH * NPIX + (size_t)v * VH_WORDS;  // words == floats (4B)
  for (int p2 = t; p2 < 3784; p2 += 256) {
    int hr = p2 / 44;           // halo row 0..85
    int hc = (p2 % 44) * 2;     // halo col (even) 0..86
    int ir = hr - 11;
    int ic0 = hc - 11, ic1 = hc - 10;
    bool rok = (ir >= 0 && ir < 64);
    float f0 = (rok && ic0 >= 0 && ic0 < 64) ? vrow[ir * 64 + ic0] : 0.f;
    float f1 = (rok && ic1 >= 0 && ic1 < 64) ? vrow[ir * 64 + ic1] : 0.f;
    uint u0 = __float_as_uint(f0), u1 = __float_as_uint(f1);
    uint h0 = (u0 + 0x7fffu + ((u0 >> 16) & 1u)) >> 16;
    uint h1 = (u1 + 0x7fffu + ((u1 >> 16) & 1u)) >> 16;
    dst[p2] = (h0 & 0xffffu) | (h1 << 16);
  }
}

// ---------------- 4) lambda_c via MFMA, UNNORMALIZED exp + S accumulation ----------
// kf sigma~0.8 -> exp<=~50, fp32-safe without max subtraction (validated R10/R11).
__global__ __launch_bounds__(256) void k_lambda_c(
    const float* __restrict__ proj, float* __restrict__ lc, float* __restrict__ S) {
  int split = blockIdx.x;  // 0..63
  int b = blockIdx.y;
  int t = threadIdx.x;
  int lane = t & 63, w = t >> 6;
  int kr = lane & 15;       // A row (k); also B col (vv offset)
  int half = lane >> 4;     // k-dim offset 8*half
  const float* kfrow = proj + ((size_t)b * NCH + ROW_KF + kr) * NPIX;
  const float* vrow  = proj + ((size_t)b * NCH + ROW_V + w * 16 + kr) * NPIX;
  f32x4 acc = (f32x4)(0.f);
  float ssum = 0.f;
  #pragma unroll
  for (int c = 0; c < 2; c++) {
    int n0 = split * 64 + c * 32 + half * 8;
    float4 fa0 = *(const float4*)(kfrow + n0);
    float4 fa1 = *(const float4*)(kfrow + n0 + 4);
    float4 fb0 = *(const float4*)(vrow + n0);
    float4 fb1 = *(const float4*)(vrow + n0 + 4);
    float e0 = __expf(fa0.x), e1 = __expf(fa0.y), e2 = __expf(fa0.z), e3 = __expf(fa0.w);
    float e4 = __expf(fa1.x), e5 = __expf(fa1.y), e6 = __expf(fa1.z), e7 = __expf(fa1.w);
    ssum += (e0 + e1 + e2 + e3) + (e4 + e5 + e6 + e7);
    bf16x8 a, bb;
    a[0] = f2bf(e0); a[1] = f2bf(e1); a[2] = f2bf(e2); a[3] = f2bf(e3);
    a[4] = f2bf(e4); a[5] = f2bf(e5); a[6] = f2bf(e6); a[7] = f2bf(e7);
    bb[0] = f2bf(fb0.x); bb[1] = f2bf(fb0.y); bb[2] = f2bf(fb0.z); bb[3] = f2bf(fb0.w);
    bb[4] = f2bf(fb1.x); bb[5] = f2bf(fb1.y); bb[6] = f2bf(fb1.z); bb[7] = f2bf(fb1.w);
    acc = __builtin_amdgcn_mfma_f32_16x16x32_bf16(a, bb, acc, 0, 0, 0);
  }
  #pragma unroll
  for (int r = 0; r < 4; r++) {
    int k = half * 4 + r;
    atomicAdd(&lc[((size_t)b * 16 + k) * 64 + w * 16 + kr], acc[r]);
  }
  if (w == 0) {   // exp values identical across waves; only wave 0 contributes S
    ssum += __shfl_xor(ssum, 16);
    ssum += __shfl_xor(ssum, 32);
    if (lane < 16) atomicAdd(&S[b * 16 + kr], ssum);
  }
}

// ---------------- 4b) normalize lc by S OUTSIDE conv (VGPR-cliff protection) -------
// R11 put lc/S inside the conv epilogue: VGPR 60->68 crossed the 64-reg occupancy
// boundary (waves/SIMD halve) and cost 7.4us. This 2us kernel keeps conv at 60.
__global__ __launch_bounds__(256) void k_lcnorm(
    float* __restrict__ lc, const float* __restrict__ S) {
  int i = blockIdx.x * 256 + threadIdx.x;   // 0..8191
  lc[i] /= S[i >> 6];
}

// ---------------- 5) MFMA implicit-im2col conv + fused epilogue (R4/R9 winner) -----
// LDS-staged E + 16-slot B-fragment ring + launch_bounds(256,2). DO NOT add ANY
// live state here: R5 (512thr), R10 (bounds(256,6)), R11 (/S epilogue) all paid
// at the register cliff. lc arrives pre-normalized.
__global__ __launch_bounds__(256, 2) void k_conv_mfma(
    const float* __restrict__ proj, const ushort* __restrict__ etw,
    const float* __restrict__ qT, const float* __restrict__ lc,
    const uint* __restrict__ vhg,
    float* __restrict__ outT, float* __restrict__ out, int mode) {
  int s = blockIdx.x;      // 0..7
  int v = blockIdx.y;      // 0..63
  int b = blockIdx.z;
  int t = threadIdx.x;
  __shared__ __align__(16) ushort vh[86 * 88];       // 15136 B halo bf16
  __shared__ __align__(16) ushort elds[23 * 64 * 8]; // 23552 B E_s chunks

  {
    const uint4* src = (const uint4*)etw + s * 1472;
    uint4* dst = (uint4*)elds;
    for (int i = t; i < 1472; i += 256) dst[i] = src[i];
  }
  if (mode != 0) {
    const uint4* vsrc = (const uint4*)(vhg + (size_t)b * NCH * NPIX + (size_t)v * VH_WORDS);
    uint4* vdst = (uint4*)vh;
    for (int i = t; i < 946; i += 256) vdst[i] = vsrc[i];
  } else {
    const float* vrow = proj + ((size_t)b * NCH + ROW_V + v) * NPIX;
    for (int i = t; i < 86 * 88; i += 256) {
      int hr = i / 88, hc = i % 88;
      int ir = hr - 11, ic = hc - 11;
      float val = (ir >= 0 && ir < 64 && ic >= 0 && ic < 64) ? vrow[ir * 64 + ic] : 0.f;
      unsigned u = __float_as_uint(val);
      vh[i] = (ushort)((u + 0x7fffu + ((u >> 16) & 1u)) >> 16);
    }
  }
  __syncthreads();

  int lane = t & 63, w = t >> 6;
  int n_ = lane & 15, q = lane >> 4;
  int rn = n_ >> 3, g = n_ & 7;

  f32x4 acc[8];
  #pragma unroll
  for (int i = 0; i < 8; i++) acc[i] = (f32x4)(0.f);

  const bf16x8* vh8 = (const bf16x8*)vh;
  const bf16x8* e8 = (const bf16x8*)elds;
  int baseA = (w * 16 + rn) * 11 + g + q;

  // prime circular fragment buffer with halo rows 0..15 (relative to baseA)
  bf16x8 bfr[16];
  #pragma unroll
  for (int r = 0; r < 16; r++)
    bfr[(r & 1) * 8 + ((r >> 1) & 7)] = vh8[baseA + r * 11];

  #pragma unroll
  for (int dy = 0; dy < 23; dy++) {
    bf16x8 ef = e8[dy * 64 + lane];
    // issue next row's read early; commit into the slot after this dy's MFMAs
    bf16x8 tmp;
    if (dy + 16 <= 36) tmp = vh8[baseA + (dy + 16) * 11];
    #pragma unroll
    for (int tt = 0; tt < 8; tt++) {
      int r = dy + 2 * tt;
      acc[tt] = __builtin_amdgcn_mfma_f32_16x16x32_bf16(
          ef, bfr[(r & 1) * 8 + ((r >> 1) & 7)], acc[tt], 0, 0, 0);
    }
    if (dy + 16 <= 36) {
      int rr = dy + 16;
      bfr[(rr & 1) * 8 + ((rr >> 1) & 7)] = tmp;
    }
  }

  float lcv[4];
  #pragma unroll
  for (int r = 0; r < 4; r++) lcv[r] = lc[((size_t)b * 16 + q * 4 + r) * 64 + v];

  if (mode != 0) {
    const float* qTb = qT + (size_t)b * 64 * NPIX;
    float* obT = outT + (size_t)b * 256 * NPIX;
    float* ob = out + (size_t)b * 256 * NPIX;
    #pragma unroll
    for (int tt = 0; tt < 8; tt++) {
      int row = w * 16 + 2 * tt + rn;
      int io = s * 512 + row * 8 + g;              // qT / outT index (coalesced)
      float lam[4];
      #pragma unroll
      for (int r = 0; r < 4; r++) lam[r] = acc[tt][r] + lcv[r];
      float y[4];
      #pragma unroll
      for (int h = 0; h < 4; h++) {
        float a = 0.f;
        #pragma unroll
        for (int r = 0; r < 4; r++)
          a += qTb[(size_t)(h * 16 + q * 4 + r) * NPIX + io] * lam[r];
        y[h] = a;
      }
      #pragma unroll
      for (int h = 0; h < 4; h++) {
        y[h] += __shfl_xor(y[h], 16);
        y[h] += __shfl_xor(y[h], 32);
      }
      if (q == 0) {
        if (mode == 2) {
          #pragma unroll
          for (int h = 0; h < 4; h++) obT[(size_t)(h * 64 + v) * NPIX + io] = y[h];
        } else {
          int p = row * 64 + 8 * g + s;
          #pragma unroll
          for (int h = 0; h < 4; h++) ob[(size_t)(h * 64 + v) * NPIX + p] = y[h];
        }
      }
    }
  } else {
    const float* qbp = proj + (size_t)b * NCH * NPIX;
    float* ob = out + (size_t)b * 256 * NPIX;
    #pragma unroll
    for (int tt = 0; tt < 8; tt++) {
      int p = (w * 16 + 2 * tt + rn) * 64 + 8 * g + s;
      float lam[4];
      #pragma unroll
      for (int r = 0; r < 4; r++) lam[r] = acc[tt][r] + lcv[r];
      float y[4];
      #pragma unroll
      for (int h = 0; h < 4; h++) {
        float a = 0.f;
        #pragma unroll
        for (int r = 0; r < 4; r++)
          a += qbp[(size_t)(h * 16 + q * 4 + r) * NPIX + p] * lam[r];
        y[h] = a;
      }
      #pragma unroll
      for (int h = 0; h < 4; h++) {
        y[h] += __shfl_xor(y[h], 16);
        y[h] += __shfl_xor(y[h], 32);
      }
      if (q == 0) {
        #pragma unroll
        for (int h = 0; h < 4; h++) ob[(size_t)(h * 64 + v) * NPIX + p] = y[h];
      }
    }
  }
}

// ---------------- 6) un-transpose: outT[b][ch][s*512+i] -> out[b][ch][p] ----------
__global__ __launch_bounds__(256) void k_outtrans(
    const float* __restrict__ outT, float* __restrict__ out) {
  int ch = blockIdx.x, b = blockIdx.y, t = threadIdx.x;
  __shared__ float buf[4608];
  const float* src = outT + ((size_t)b * 256 + ch) * NPIX;
  for (int it = 0; it < 16; it++) {
    int idx = it * 256 + t;           // s*512 + i
    int s = idx >> 9, i = idx & 511;
    int p = (i >> 3) * 64 + (i & 7) * 8 + s;
    buf[p + (p >> 3)] = src[idx];
  }
  __syncthreads();
  float* dst = out + ((size_t)b * 256 + ch) * NPIX;
  for (int it = 0; it < 16; it++) {
    int p = it * 256 + t;
    dst[p] = buf[p + (p >> 3)];
  }
}

extern "C" void kernel_launch(void* const* d_in, const int* in_sizes, int n_in,
                              void* d_out, int out_size, void* d_ws, size_t ws_size,
                              hipStream_t stream) {
  const float* x    = (const float*)d_in[0];
  const float* Wq   = (const float*)d_in[1];
  const float* qg   = (const float*)d_in[2];
  const float* qbta = (const float*)d_in[3];
  const float* qm   = (const float*)d_in[4];
  const float* qv   = (const float*)d_in[5];
  const float* Wk   = (const float*)d_in[6];
  const float* Wv   = (const float*)d_in[7];
  const float* vg   = (const float*)d_in[8];
  const float* vb   = (const float*)d_in[9];
  const float* vm   = (const float*)d_in[10];
  const float* vvar = (const float*)d_in[11];
  const float* emb  = (const float*)d_in[12];
  float* ws   = (float*)d_ws;
  float* Wt   = ws + WP_OFF;
  float* bp   = ws + BIAS_OFF;
  float* proj = ws + PROJ_OFF;
  float* Sw   = ws + RMAX_OFF;
  float* lcw  = ws + LC_OFF;
  ushort* etw = (ushort*)(ws + ET_OFF);
  float* qT   = ws + QT_OFF;
  float* outT = ws + OUTT_OFF;
  float* out  = (float*)d_out;
  uint* vhg   = (uint*)proj;      // dead q-row region of proj, reused per (b,v)
  ushort* wtA = (ushort*)qT;      // qT region head; consumed before k_qtrans writes

  size_t wsf = ws_size / sizeof(float);
  int mode = (wsf >= WS_NEED_FULL) ? 2 : ((wsf >= WS_NEED_QT) ? 1 : 0);

  hipLaunchKernelGGL(k_prep, dim3(512), dim3(256), 0, stream,
                     Wq, qg, qbta, qm, qv, Wk, Wv, vg, vb, vm, vvar, emb, Wt, bp, etw);
  hipMemsetAsync(Sw, 0, 8448 * sizeof(float), stream);   // S (256) + lc (8192)
  if (mode >= 1) {
    hipLaunchKernelGGL(k_wprep, dim3(18), dim3(256), 0, stream, Wt, wtA);
    hipLaunchKernelGGL(k_projm, dim3(64, 8), dim3(256), 0, stream, x, wtA, bp, proj);
    hipLaunchKernelGGL(k_qtrans, dim3(64, 8), dim3(256), 0, stream, proj, qT);
    hipLaunchKernelGGL(k_vhalo, dim3(64, 8), dim3(256), 0, stream, proj, vhg);
  } else {
    hipLaunchKernelGGL(k_proj, dim3(16, 8, 8), dim3(256), 0, stream, x, Wt, bp, proj);
  }
  hipLaunchKernelGGL(k_lambda_c, dim3(64, 8), dim3(256), 0, stream, proj, lcw, Sw);
  hipLaunchKernelGGL(k_lcnorm, dim3(32), dim3(256), 0, stream, lcw, Sw);
  hipLaunchKernelGGL(k_conv_mfma, dim3(8, 64, 8), dim3(256), 0, stream,
                     proj, etw, qT, lcw, vhg, outT, out, mode);
  if (mode == 2)
    hipLaunchKernelGGL(k_outtrans, dim3(256, 8), dim3(256), 0, stream, outT, out);
}

// Round 13
// 212.190 us; speedup vs baseline: 2.6359x; 1.0086x over previous
//
#include <hip/hip_runtime.h>

typedef __attribute__((ext_vector_type(8))) short bf16x8;
typedef __attribute__((ext_vector_type(4))) float f32x4;

#define EPS 1e-5f
#define B 8
#define C 256
#define NPIX 4096      // 64*64
#define NCH 144        // rows: 0..63 q_bn, 64..127 v_bn, 128..143 kf(raw)
#define ROW_V 64
#define ROW_KF 128
#define PAD 11
#define VH_WORDS 3840  // 4-byte words reserved per (v,b) halo (3784 used)

// workspace layout (float offsets)
#define WP_OFF    0u          // Wt transposed: 256*144 = 36864
#define BIAS_OFF  36864u      // 144
#define PROJ_OFF  37120u      // 8*144*4096 = 4718592
#define RMAX_OFF  4755712u    // S: 128 softmax denominators (+128 pad)
#define LC_OFF    4755968u    // 8*16*64 = 8192 (raw, normalized by k_lcnorm)
#define ET_OFF    4764160u    // E variants: 94208 ushort = 47104 floats
#define QT_OFF    4811264u    // qT: 8*64*4096 = 2097152 (wtA borrows its head pre-qtrans)
#define OUTT_OFF  6908416u    // outT: 8*256*4096 = 8388608 (end 15297024 floats)
#define WS_NEED_QT    6908416u
#define WS_NEED_FULL  15297024u

__device__ inline short f2bf(float f) {
  unsigned u = __float_as_uint(f);
  return (short)((u + 0x7fffu + ((u >> 16) & 1u)) >> 16);
}

// ---------------- 1) fused prep: blocks 0..143 fold BN into Wt; 144..511 build E ----
__global__ __launch_bounds__(256) void k_prep(
    const float* __restrict__ Wq, const float* __restrict__ qg, const float* __restrict__ qb,
    const float* __restrict__ qm, const float* __restrict__ qv,
    const float* __restrict__ Wk, const float* __restrict__ Wv,
    const float* __restrict__ vg, const float* __restrict__ vb,
    const float* __restrict__ vm, const float* __restrict__ vvar,
    const float* __restrict__ emb,
    float* __restrict__ Wt, float* __restrict__ biasp, ushort* __restrict__ etw) {
  int t = threadIdx.x;
  if (blockIdx.x < 144) {
    int o = blockIdx.x;   // 0..143
    const float* src; float s, bias;
    if (o < 64) {
      s = qg[o] * rsqrtf(qv[o] + EPS); bias = qb[o] - qm[o] * s; src = Wq + o * C;
    } else if (o < 128) {
      int i = o - 64;
      s = vg[i] * rsqrtf(vvar[i] + EPS); bias = vb[i] - vm[i] * s; src = Wv + i * C;
    } else {
      int i = o - 128; s = 1.f; bias = 0.f; src = Wk + i * C;
    }
    Wt[t * NCH + o] = src[t] * s;
    if (t == 0) biasp[o] = bias;
  } else {
    int i = (blockIdx.x - 144) * 256 + t;   // 0..94207
    int s = i / 11776;
    int r = i % 11776;
    int dy = r / 512;
    int l = (r / 8) % 64;
    int jj = r % 8;
    int f = l & 15, q = l >> 4;
    int dx = q * 8 + jj - s;
    float val = (dx >= 0 && dx < 23) ? emb[f * 529 + dy * 23 + dx] : 0.f;
    unsigned u = __float_as_uint(val);
    etw[i] = (ushort)((u + 0x7fffu + ((u >> 16) & 1u)) >> 16);
  }
}

// ---------------- 1c) prepack Wt into MFMA A-fragment order (bf16) ----------------
__global__ __launch_bounds__(256) void k_wprep(
    const float* __restrict__ Wt, ushort* __restrict__ wtA) {
  int i = blockIdx.x * 256 + threadIdx.x;   // 0..4607
  int mt = i >> 9;
  int rest = i & 511;
  int kt = rest >> 6;
  int lane = rest & 63;
  int m = mt * 16 + (lane & 15);
  int c0 = kt * 32 + (lane >> 4) * 8;
  ushort* dst = wtA + (size_t)i * 8;
  #pragma unroll
  for (int j = 0; j < 8; j++) {
    float v = Wt[(c0 + j) * NCH + m];
    unsigned u = __float_as_uint(v);
    dst[j] = (ushort)((u + 0x7fffu + ((u >> 16) & 1u)) >> 16);
  }
}

// ---------------- 2) projection as MFMA GEMM: proj = Wt^T x + bias ----------------
__global__ __launch_bounds__(256) void k_projm(
    const float* __restrict__ x, const ushort* __restrict__ wtA,
    const float* __restrict__ biasp, float* __restrict__ proj) {
  int ntile = blockIdx.x;  // 0..63
  int b = blockIdx.y;
  int t = threadIdx.x;
  int lane = t & 63, w = t >> 6;
  int px = ntile * 64 + w * 16 + (lane & 15);
  int kq = lane >> 4;
  const float* xb = x + (size_t)b * C * NPIX + px;
  const bf16x8* A = (const bf16x8*)wtA;
  f32x4 acc[9];
  #pragma unroll
  for (int i = 0; i < 9; i++) acc[i] = (f32x4)(0.f);
  #pragma unroll 2
  for (int kt = 0; kt < 8; kt++) {
    int c0 = kt * 32 + kq * 8;
    bf16x8 bb;
    #pragma unroll
    for (int j = 0; j < 8; j++) bb[j] = f2bf(xb[(size_t)(c0 + j) * NPIX]);
    #pragma unroll
    for (int mt = 0; mt < 9; mt++) {
      bf16x8 a = A[(mt * 8 + kt) * 64 + lane];
      acc[mt] = __builtin_amdgcn_mfma_f32_16x16x32_bf16(a, bb, acc[mt], 0, 0, 0);
    }
  }
  float* pb = proj + (size_t)b * NCH * NPIX + px;
  #pragma unroll
  for (int mt = 0; mt < 9; mt++) {
    #pragma unroll
    for (int r = 0; r < 4; r++) {
      int ch = mt * 16 + kq * 4 + r;
      pb[(size_t)ch * NPIX] = acc[mt][r] + biasp[ch];
    }
  }
}

// ---------------- 2-fallback) VALU projection (mode 0 only) ----------
__global__ __launch_bounds__(256) void k_proj(
    const float* __restrict__ x, const float* __restrict__ Wt,
    const float* __restrict__ biasp, float* __restrict__ proj) {
  int tile = blockIdx.x;  // 0..15
  int g = blockIdx.y;     // 0..7 (18 ch each)
  int b = blockIdx.z;
  int t = threadIdx.x;
  int px = tile * 256 + t;
  const float* xb = x + (size_t)b * C * NPIX + px;
  float acc[18];
  #pragma unroll
  for (int i = 0; i < 18; i++) acc[i] = 0.f;
  #pragma unroll 4
  for (int c = 0; c < C; c++) {
    float xv = xb[(size_t)c * NPIX];
    const float* wrow = Wt + c * NCH + g * 18;   // uniform -> s_load
    #pragma unroll
    for (int i = 0; i < 18; i++) acc[i] += xv * wrow[i];
  }
  float* ob = proj + ((size_t)b * NCH + g * 18) * NPIX + px;
  #pragma unroll
  for (int i = 0; i < 18; i++) ob[(size_t)i * NPIX] = acc[i] + biasp[g * 18 + i];
}

// ---------------- 2b) transpose q rows: proj[b][ch][p] -> qT[b][ch][s*512+i] ----------
__global__ __launch_bounds__(256) void k_qtrans(
    const float* __restrict__ proj, float* __restrict__ qT) {
  int ch = blockIdx.x, b = blockIdx.y, t = threadIdx.x;
  __shared__ float buf[4608];
  const float* src = proj + ((size_t)b * NCH + ch) * NPIX;
  for (int it = 0; it < 16; it++) {
    int p = it * 256 + t;
    buf[p + (p >> 3)] = src[p];
  }
  __syncthreads();
  float* dst = qT + ((size_t)b * 64 + ch) * NPIX;
  for (int it = 0; it < 16; it++) {
    int idx = it * 256 + t;           // s*512 + i
    int s = idx >> 9, i = idx & 511;
    int p = (i >> 3) * 64 + (i & 7) * 8 + s;
    dst[idx] = buf[p + (p >> 3)];
  }
}

// ---------------- 2c) prebuild bf16 halos: one 86x88 halo per (v,b) ----------------
__global__ __launch_bounds__(256) void k_vhalo(
    const float* __restrict__ proj, uint* __restrict__ vhg) {
  int v = blockIdx.x, b = blockIdx.y, t = threadIdx.x;
  const float* vrow = proj + ((size_t)b * NCH + ROW_V + v) * NPIX;
  uint* dst = vhg + (size_t)b * NCH * NPIX + (size_t)v * VH_WORDS;  // words == floats (4B)
  for (int p2 = t; p2 < 3784; p2 += 256) {
    int hr = p2 / 44;           // halo row 0..85
    int hc = (p2 % 44) * 2;     // halo col (even) 0..86
    int ir = hr - 11;
    int ic0 = hc - 11, ic1 = hc - 10;
    bool rok = (ir >= 0 && ir < 64);
    float f0 = (rok && ic0 >= 0 && ic0 < 64) ? vrow[ir * 64 + ic0] : 0.f;
    float f1 = (rok && ic1 >= 0 && ic1 < 64) ? vrow[ir * 64 + ic1] : 0.f;
    uint u0 = __float_as_uint(f0), u1 = __float_as_uint(f1);
    uint h0 = (u0 + 0x7fffu + ((u0 >> 16) & 1u)) >> 16;
    uint h1 = (u1 + 0x7fffu + ((u1 >> 16) & 1u)) >> 16;
    dst[p2] = (h0 & 0xffffu) | (h1 << 16);
  }
}

// ---------------- 4) lambda_c via MFMA, UNNORMALIZED exp + S accumulation ----------
__global__ __launch_bounds__(256) void k_lambda_c(
    const float* __restrict__ proj, float* __restrict__ lc, float* __restrict__ S) {
  int split = blockIdx.x;  // 0..63
  int b = blockIdx.y;
  int t = threadIdx.x;
  int lane = t & 63, w = t >> 6;
  int kr = lane & 15;       // A row (k); also B col (vv offset)
  int half = lane >> 4;     // k-dim offset 8*half
  const float* kfrow = proj + ((size_t)b * NCH + ROW_KF + kr) * NPIX;
  const float* vrow  = proj + ((size_t)b * NCH + ROW_V + w * 16 + kr) * NPIX;
  f32x4 acc = (f32x4)(0.f);
  float ssum = 0.f;
  #pragma unroll
  for (int c = 0; c < 2; c++) {
    int n0 = split * 64 + c * 32 + half * 8;
    float4 fa0 = *(const float4*)(kfrow + n0);
    float4 fa1 = *(const float4*)(kfrow + n0 + 4);
    float4 fb0 = *(const float4*)(vrow + n0);
    float4 fb1 = *(const float4*)(vrow + n0 + 4);
    float e0 = __expf(fa0.x), e1 = __expf(fa0.y), e2 = __expf(fa0.z), e3 = __expf(fa0.w);
    float e4 = __expf(fa1.x), e5 = __expf(fa1.y), e6 = __expf(fa1.z), e7 = __expf(fa1.w);
    ssum += (e0 + e1 + e2 + e3) + (e4 + e5 + e6 + e7);
    bf16x8 a, bb;
    a[0] = f2bf(e0); a[1] = f2bf(e1); a[2] = f2bf(e2); a[3] = f2bf(e3);
    a[4] = f2bf(e4); a[5] = f2bf(e5); a[6] = f2bf(e6); a[7] = f2bf(e7);
    bb[0] = f2bf(fb0.x); bb[1] = f2bf(fb0.y); bb[2] = f2bf(fb0.z); bb[3] = f2bf(fb0.w);
    bb[4] = f2bf(fb1.x); bb[5] = f2bf(fb1.y); bb[6] = f2bf(fb1.z); bb[7] = f2bf(fb1.w);
    acc = __builtin_amdgcn_mfma_f32_16x16x32_bf16(a, bb, acc, 0, 0, 0);
  }
  #pragma unroll
  for (int r = 0; r < 4; r++) {
    int k = half * 4 + r;
    atomicAdd(&lc[((size_t)b * 16 + k) * 64 + w * 16 + kr], acc[r]);
  }
  if (w == 0) {   // exp values identical across waves; only wave 0 contributes S
    ssum += __shfl_xor(ssum, 16);
    ssum += __shfl_xor(ssum, 32);
    if (lane < 16) atomicAdd(&S[b * 16 + kr], ssum);
  }
}

// ---------------- 4b) normalize lc by S OUTSIDE conv (VGPR-cliff protection) -------
__global__ __launch_bounds__(256) void k_lcnorm(
    float* __restrict__ lc, const float* __restrict__ S) {
  int i = blockIdx.x * 256 + threadIdx.x;   // 0..8191
  lc[i] /= S[i >> 6];
}

// ---------------- 5) MFMA implicit-im2col conv + fused epilogue ----------
// R12 wave structure, but E read DIRECTLY from global (etw: 188KB total across
// 8 variants, fully L2-resident) instead of LDS-staged. LDS 38.9KB -> 15.1KB:
// occupancy cap moves from LDS (4 blocks/CU) to VGPR (8 blocks/CU at VGPR<=64).
// CRITICAL: launch_bounds stays (256,2) -- R10's failure was the (256,6) VGPR
// clamp (60->40, spilled ring, 1.6GB scratch), NOT E-from-global itself.
// Spill tripwire: WRITE_SIZE must stay 32768 KB.
__global__ __launch_bounds__(256, 2) void k_conv_mfma(
    const float* __restrict__ proj, const ushort* __restrict__ etw,
    const float* __restrict__ qT, const float* __restrict__ lc,
    const uint* __restrict__ vhg,
    float* __restrict__ outT, float* __restrict__ out, int mode) {
  int s = blockIdx.x;      // 0..7
  int v = blockIdx.y;      // 0..63
  int b = blockIdx.z;
  int t = threadIdx.x;
  __shared__ __align__(16) ushort vh[86 * 88];       // 15136 B halo bf16

  if (mode != 0) {
    const uint4* vsrc = (const uint4*)(vhg + (size_t)b * NCH * NPIX + (size_t)v * VH_WORDS);
    uint4* vdst = (uint4*)vh;
    for (int i = t; i < 946; i += 256) vdst[i] = vsrc[i];
  } else {
    const float* vrow = proj + ((size_t)b * NCH + ROW_V + v) * NPIX;
    for (int i = t; i < 86 * 88; i += 256) {
      int hr = i / 88, hc = i % 88;
      int ir = hr - 11, ic = hc - 11;
      float val = (ir >= 0 && ir < 64 && ic >= 0 && ic < 64) ? vrow[ir * 64 + ic] : 0.f;
      unsigned u = __float_as_uint(val);
      vh[i] = (ushort)((u + 0x7fffu + ((u >> 16) & 1u)) >> 16);
    }
  }
  __syncthreads();

  int lane = t & 63, w = t >> 6;
  int n_ = lane & 15, q = lane >> 4;
  int rn = n_ >> 3, g = n_ & 7;

  f32x4 acc[8];
  #pragma unroll
  for (int i = 0; i < 8; i++) acc[i] = (f32x4)(0.f);

  const bf16x8* vh8 = (const bf16x8*)vh;
  const bf16x8* e8 = (const bf16x8*)etw + (size_t)s * 1472;  // global, L2-hot
  int baseA = (w * 16 + rn) * 11 + g + q;

  // prime circular fragment buffer with halo rows 0..15 (relative to baseA)
  bf16x8 bfr[16];
  #pragma unroll
  for (int r = 0; r < 16; r++)
    bfr[(r & 1) * 8 + ((r >> 1) & 7)] = vh8[baseA + r * 11];

  #pragma unroll
  for (int dy = 0; dy < 23; dy++) {
    bf16x8 ef = e8[dy * 64 + lane];
    // issue next row's read early; commit into the slot after this dy's MFMAs
    bf16x8 tmp;
    if (dy + 16 <= 36) tmp = vh8[baseA + (dy + 16) * 11];
    #pragma unroll
    for (int tt = 0; tt < 8; tt++) {
      int r = dy + 2 * tt;
      acc[tt] = __builtin_amdgcn_mfma_f32_16x16x32_bf16(
          ef, bfr[(r & 1) * 8 + ((r >> 1) & 7)], acc[tt], 0, 0, 0);
    }
    if (dy + 16 <= 36) {
      int rr = dy + 16;
      bfr[(rr & 1) * 8 + ((rr >> 1) & 7)] = tmp;
    }
  }

  float lcv[4];
  #pragma unroll
  for (int r = 0; r < 4; r++) lcv[r] = lc[((size_t)b * 16 + q * 4 + r) * 64 + v];

  if (mode != 0) {
    const float* qTb = qT + (size_t)b * 64 * NPIX;
    float* obT = outT + (size_t)b * 256 * NPIX;
    float* ob = out + (size_t)b * 256 * NPIX;
    #pragma unroll
    for (int tt = 0; tt < 8; tt++) {
      int row = w * 16 + 2 * tt + rn;
      int io = s * 512 + row * 8 + g;              // qT / outT index (coalesced)
      float lam[4];
      #pragma unroll
      for (int r = 0; r < 4; r++) lam[r] = acc[tt][r] + lcv[r];
      float y[4];
      #pragma unroll
      for (int h = 0; h < 4; h++) {
        float a = 0.f;
        #pragma unroll
        for (int r = 0; r < 4; r++)
          a += qTb[(size_t)(h * 16 + q * 4 + r) * NPIX + io] * lam[r];
        y[h] = a;
      }
      #pragma unroll
      for (int h = 0; h < 4; h++) {
        y[h] += __shfl_xor(y[h], 16);
        y[h] += __shfl_xor(y[h], 32);
      }
      if (q == 0) {
        if (mode == 2) {
          #pragma unroll
          for (int h = 0; h < 4; h++) obT[(size_t)(h * 64 + v) * NPIX + io] = y[h];
        } else {
          int p = row * 64 + 8 * g + s;
          #pragma unroll
          for (int h = 0; h < 4; h++) ob[(size_t)(h * 64 + v) * NPIX + p] = y[h];
        }
      }
    }
  } else {
    const float* qbp = proj + (size_t)b * NCH * NPIX;
    float* ob = out + (size_t)b * 256 * NPIX;
    #pragma unroll
    for (int tt = 0; tt < 8; tt++) {
      int p = (w * 16 + 2 * tt + rn) * 64 + 8 * g + s;
      float lam[4];
      #pragma unroll
      for (int r = 0; r < 4; r++) lam[r] = acc[tt][r] + lcv[r];
      float y[4];
      #pragma unroll
      for (int h = 0; h < 4; h++) {
        float a = 0.f;
        #pragma unroll
        for (int r = 0; r < 4; r++)
          a += qbp[(size_t)(h * 16 + q * 4 + r) * NPIX + p] * lam[r];
        y[h] = a;
      }
      #pragma unroll
      for (int h = 0; h < 4; h++) {
        y[h] += __shfl_xor(y[h], 16);
        y[h] += __shfl_xor(y[h], 32);
      }
      if (q == 0) {
        #pragma unroll
        for (int h = 0; h < 4; h++) ob[(size_t)(h * 64 + v) * NPIX + p] = y[h];
      }
    }
  }
}

// ---------------- 6) un-transpose: outT[b][ch][s*512+i] -> out[b][ch][p] ----------
__global__ __launch_bounds__(256) void k_outtrans(
    const float* __restrict__ outT, float* __restrict__ out) {
  int ch = blockIdx.x, b = blockIdx.y, t = threadIdx.x;
  __shared__ float buf[4608];
  const float* src = outT + ((size_t)b * 256 + ch) * NPIX;
  for (int it = 0; it < 16; it++) {
    int idx = it * 256 + t;           // s*512 + i
    int s = idx >> 9, i = idx & 511;
    int p = (i >> 3) * 64 + (i & 7) * 8 + s;
    buf[p + (p >> 3)] = src[idx];
  }
  __syncthreads();
  float* dst = out + ((size_t)b * 256 + ch) * NPIX;
  for (int it = 0; it < 16; it++) {
    int p = it * 256 + t;
    dst[p] = buf[p + (p >> 3)];
  }
}

extern "C" void kernel_launch(void* const* d_in, const int* in_sizes, int n_in,
                              void* d_out, int out_size, void* d_ws, size_t ws_size,
                              hipStream_t stream) {
  const float* x    = (const float*)d_in[0];
  const float* Wq   = (const float*)d_in[1];
  const float* qg   = (const float*)d_in[2];
  const float* qbta = (const float*)d_in[3];
  const float* qm   = (const float*)d_in[4];
  const float* qv   = (const float*)d_in[5];
  const float* Wk   = (const float*)d_in[6];
  const float* Wv   = (const float*)d_in[7];
  const float* vg   = (const float*)d_in[8];
  const float* vb   = (const float*)d_in[9];
  const float* vm   = (const float*)d_in[10];
  const float* vvar = (const float*)d_in[11];
  const float* emb  = (const float*)d_in[12];
  float* ws   = (float*)d_ws;
  float* Wt   = ws + WP_OFF;
  float* bp   = ws + BIAS_OFF;
  float* proj = ws + PROJ_OFF;
  float* Sw   = ws + RMAX_OFF;
  float* lcw  = ws + LC_OFF;
  ushort* etw = (ushort*)(ws + ET_OFF);
  float* qT   = ws + QT_OFF;
  float* outT = ws + OUTT_OFF;
  float* out  = (float*)d_out;
  uint* vhg   = (uint*)proj;      // dead q-row region of proj, reused per (b,v)
  ushort* wtA = (ushort*)qT;      // qT region head; consumed before k_qtrans writes

  size_t wsf = ws_size / sizeof(float);
  int mode = (wsf >= WS_NEED_FULL) ? 2 : ((wsf >= WS_NEED_QT) ? 1 : 0);

  hipLaunchKernelGGL(k_prep, dim3(512), dim3(256), 0, stream,
                     Wq, qg, qbta, qm, qv, Wk, Wv, vg, vb, vm, vvar, emb, Wt, bp, etw);
  hipMemsetAsync(Sw, 0, 8448 * sizeof(float), stream);   // S (256) + lc (8192)
  if (mode >= 1) {
    hipLaunchKernelGGL(k_wprep, dim3(18), dim3(256), 0, stream, Wt, wtA);
    hipLaunchKernelGGL(k_projm, dim3(64, 8), dim3(256), 0, stream, x, wtA, bp, proj);
    hipLaunchKernelGGL(k_qtrans, dim3(64, 8), dim3(256), 0, stream, proj, qT);
    hipLaunchKernelGGL(k_vhalo, dim3(64, 8), dim3(256), 0, stream, proj, vhg);
  } else {
    hipLaunchKernelGGL(k_proj, dim3(16, 8, 8), dim3(256), 0, stream, x, Wt, bp, proj);
  }
  hipLaunchKernelGGL(k_lambda_c, dim3(64, 8), dim3(256), 0, stream, proj, lcw, Sw);
  hipLaunchKernelGGL(k_lcnorm, dim3(32), dim3(256), 0, stream, lcw, Sw);
  hipLaunchKernelGGL(k_conv_mfma, dim3(8, 64, 8), dim3(256), 0, stream,
                     proj, etw, qT, lcw, vhg, outT, out, mode);
  if (mode == 2)
    hipLaunchKernelGGL(k_outtrans, dim3(256, 8), dim3(256), 0, stream, outT, out);
}

// Round 14
// 204.841 us; speedup vs baseline: 2.7305x; 1.0359x over previous
//
#include <hip/hip_runtime.h>

typedef __attribute__((ext_vector_type(8))) short bf16x8;
typedef __attribute__((ext_vector_type(4))) float f32x4;

#define EPS 1e-5f
#define B 8
#define C 256
#define NPIX 4096      // 64*64
#define NCH 144        // rows: 0..63 q (dead in mode>=1), 64..127 v_bn, 128..143 kf
#define ROW_V 64
#define ROW_KF 128
#define PAD 11
#define VH_WORDS 3840  // 4-byte words reserved per (v,b) halo (3784 used)

// workspace layout (float offsets)
#define WP_OFF    0u          // Wt transposed: 256*144 = 36864 (mode-0 fallback only)
#define BIAS_OFF  36864u      // 144
#define PROJ_OFF  37120u      // 8*144*4096 = 4718592 (q-row region doubles as vhg)
#define RMAX_OFF  4755712u    // S: 128 softmax denominators (+128 pad)
#define LC_OFF    4755968u    // 8*16*64 = 8192 (raw, normalized by k_lcnorm)
#define ET_OFF    4764160u    // E variants: 94208 ushort = 47104 floats
#define QT_OFF    4811264u    // qT: 8*64*4096 = 2097152
#define OUTT_OFF  6908416u    // outT: 8*256*4096 = 8388608 (end 15297024 floats)
#define WS_NEED_QT    6908416u
#define WS_NEED_FULL  15297024u

__device__ inline short f2bf(float f) {
  unsigned u = __float_as_uint(f);
  return (short)((u + 0x7fffu + ((u >> 16) & 1u)) >> 16);
}

// ---------------- 1) fused prep ----------------
// blocks 0..143: fold BN into Wt (mode-0 fallback + bias)
// blocks 144..511: build 8 shifted bf16 E variants
// blocks 512..529: pack wtA (MFMA A-fragments) DIRECTLY from raw weights
// blocks 530..2449: zero the vhg halo region (pads must be 0; interiors
//                   overwritten by k_projm later in the stream)
__global__ __launch_bounds__(256) void k_prep(
    const float* __restrict__ Wq, const float* __restrict__ qg, const float* __restrict__ qb,
    const float* __restrict__ qm, const float* __restrict__ qv,
    const float* __restrict__ Wk, const float* __restrict__ Wv,
    const float* __restrict__ vg, const float* __restrict__ vb,
    const float* __restrict__ vm, const float* __restrict__ vvar,
    const float* __restrict__ emb,
    float* __restrict__ Wt, float* __restrict__ biasp, ushort* __restrict__ etw,
    ushort* __restrict__ wtA, uint* __restrict__ vhg) {
  int t = threadIdx.x;
  int blk = blockIdx.x;
  if (blk < 144) {
    int o = blk;
    const float* src; float s, bias;
    if (o < 64) {
      s = qg[o] * rsqrtf(qv[o] + EPS); bias = qb[o] - qm[o] * s; src = Wq + o * C;
    } else if (o < 128) {
      int i = o - 64;
      s = vg[i] * rsqrtf(vvar[i] + EPS); bias = vb[i] - vm[i] * s; src = Wv + i * C;
    } else {
      int i = o - 128; s = 1.f; bias = 0.f; src = Wk + i * C;
    }
    Wt[t * NCH + o] = src[t] * s;
    if (t == 0) biasp[o] = bias;
  } else if (blk < 512) {
    int i = (blk - 144) * 256 + t;   // 0..94207
    int s = i / 11776;
    int r = i % 11776;
    int dy = r / 512;
    int l = (r / 8) % 64;
    int jj = r % 8;
    int f = l & 15, q = l >> 4;
    int dx = q * 8 + jj - s;
    float val = (dx >= 0 && dx < 23) ? emb[f * 529 + dy * 23 + dx] : 0.f;
    etw[i] = (ushort)f2bf(val);
  } else if (blk < 530) {
    int i = (blk - 512) * 256 + t;   // 0..4607
    int mt = i >> 9;
    int rest = i & 511;
    int kt = rest >> 6;
    int lane = rest & 63;
    int m = mt * 16 + (lane & 15);
    int c0 = kt * 32 + (lane >> 4) * 8;
    const float* src; float s;
    if (m < 64) { s = qg[m] * rsqrtf(qv[m] + EPS); src = Wq + m * C; }
    else if (m < 128) { int ii = m - 64; s = vg[ii] * rsqrtf(vvar[ii] + EPS); src = Wv + ii * C; }
    else { s = 1.f; src = Wk + (m - 128) * C; }
    ushort* dst = wtA + (size_t)i * 8;
    #pragma unroll
    for (int j = 0; j < 8; j++) dst[j] = (ushort)f2bf(src[c0 + j] * s);
  } else {
    int zi = (blk - 530) * 256 + t;  // 0..491519 uint4s
    int bb = zi / 61440, w4 = zi % 61440;   // 61440 uint4 = 245760 words = 64 halos
    uint4 z; z.x = z.y = z.z = z.w = 0u;
    ((uint4*)vhg)[(size_t)bb * 147456 + w4] = z;  // 147456 = per-b proj stride in uint4
  }
}

// ---------------- 2) projection MFMA GEMM with fused qT + halo-interior writes -----
// row = ntile is constant per block (px = ntile*64 + col), so:
//   qT idx  = (col&7)*512 + ntile*8 + (col>>3)   (q channels 0..63, replaces k_qtrans)
//   halo u16 = (ntile+11)*88 + col+11            (v channels, replaces k_vhalo interior)
// proj written only for v+kf rows (lambda_c reads them); q rows never materialized.
__global__ __launch_bounds__(256) void k_projm(
    const float* __restrict__ x, const ushort* __restrict__ wtA,
    const float* __restrict__ biasp, float* __restrict__ proj,
    float* __restrict__ qT, uint* __restrict__ vhg) {
  int ntile = blockIdx.x;  // 0..63 (= pixel row)
  int b = blockIdx.y;
  int t = threadIdx.x;
  int lane = t & 63, w = t >> 6;
  int col = w * 16 + (lane & 15);
  int px = ntile * 64 + col;
  int kq = lane >> 4;
  const float* xb = x + (size_t)b * C * NPIX + px;
  const bf16x8* A = (const bf16x8*)wtA;
  f32x4 acc[9];
  #pragma unroll
  for (int i = 0; i < 9; i++) acc[i] = (f32x4)(0.f);
  #pragma unroll 2
  for (int kt = 0; kt < 8; kt++) {
    int c0 = kt * 32 + kq * 8;
    bf16x8 bb;
    #pragma unroll
    for (int j = 0; j < 8; j++) bb[j] = f2bf(xb[(size_t)(c0 + j) * NPIX]);
    #pragma unroll
    for (int mt = 0; mt < 9; mt++) {
      bf16x8 a = A[(mt * 8 + kt) * 64 + lane];
      acc[mt] = __builtin_amdgcn_mfma_f32_16x16x32_bf16(a, bb, acc[mt], 0, 0, 0);
    }
  }
  // q channels -> qT directly
  int idxT = (col & 7) * 512 + ntile * 8 + (col >> 3);
  float* qTb = qT + (size_t)b * 64 * NPIX;
  #pragma unroll
  for (int mt = 0; mt < 4; mt++) {
    #pragma unroll
    for (int r = 0; r < 4; r++) {
      int ch = mt * 16 + kq * 4 + r;
      qTb[(size_t)ch * NPIX + idxT] = acc[mt][r] + biasp[ch];
    }
  }
  // v + kf channels -> proj rows (lambda_c input)
  float* pb = proj + (size_t)b * NCH * NPIX + px;
  #pragma unroll
  for (int mt = 4; mt < 9; mt++) {
    #pragma unroll
    for (int r = 0; r < 4; r++) {
      int ch = mt * 16 + kq * 4 + r;
      pb[(size_t)ch * NPIX] = acc[mt][r] + biasp[ch];
    }
  }
  // v channels -> halo interior (bf16), pads pre-zeroed by k_prep
  ushort* hb = (ushort*)vhg;
  size_t hbase = (size_t)b * NCH * NPIX * 2 + (size_t)(ntile + 11) * 88 + col + 11;
  #pragma unroll
  for (int mt = 4; mt < 8; mt++) {
    #pragma unroll
    for (int r = 0; r < 4; r++) {
      int ch = mt * 16 + kq * 4 + r;
      int v = ch - 64;
      hb[hbase + (size_t)v * (VH_WORDS * 2)] = (ushort)f2bf(acc[mt][r] + biasp[ch]);
    }
  }
}

// ---------------- 2-fallback) VALU projection (mode 0 only) ----------
__global__ __launch_bounds__(256) void k_proj(
    const float* __restrict__ x, const float* __restrict__ Wt,
    const float* __restrict__ biasp, float* __restrict__ proj) {
  int tile = blockIdx.x;  // 0..15
  int g = blockIdx.y;     // 0..7 (18 ch each)
  int b = blockIdx.z;
  int t = threadIdx.x;
  int px = tile * 256 + t;
  const float* xb = x + (size_t)b * C * NPIX + px;
  float acc[18];
  #pragma unroll
  for (int i = 0; i < 18; i++) acc[i] = 0.f;
  #pragma unroll 4
  for (int c = 0; c < C; c++) {
    float xv = xb[(size_t)c * NPIX];
    const float* wrow = Wt + c * NCH + g * 18;   // uniform -> s_load
    #pragma unroll
    for (int i = 0; i < 18; i++) acc[i] += xv * wrow[i];
  }
  float* ob = proj + ((size_t)b * NCH + g * 18) * NPIX + px;
  #pragma unroll
  for (int i = 0; i < 18; i++) ob[(size_t)i * NPIX] = acc[i] + biasp[g * 18 + i];
}

// ---------------- 4) lambda_c via MFMA, UNNORMALIZED exp + S accumulation ----------
__global__ __launch_bounds__(256) void k_lambda_c(
    const float* __restrict__ proj, float* __restrict__ lc, float* __restrict__ S) {
  int split = blockIdx.x;  // 0..63
  int b = blockIdx.y;
  int t = threadIdx.x;
  int lane = t & 63, w = t >> 6;
  int kr = lane & 15;       // A row (k); also B col (vv offset)
  int half = lane >> 4;     // k-dim offset 8*half
  const float* kfrow = proj + ((size_t)b * NCH + ROW_KF + kr) * NPIX;
  const float* vrow  = proj + ((size_t)b * NCH + ROW_V + w * 16 + kr) * NPIX;
  f32x4 acc = (f32x4)(0.f);
  float ssum = 0.f;
  #pragma unroll
  for (int c = 0; c < 2; c++) {
    int n0 = split * 64 + c * 32 + half * 8;
    float4 fa0 = *(const float4*)(kfrow + n0);
    float4 fa1 = *(const float4*)(kfrow + n0 + 4);
    float4 fb0 = *(const float4*)(vrow + n0);
    float4 fb1 = *(const float4*)(vrow + n0 + 4);
    float e0 = __expf(fa0.x), e1 = __expf(fa0.y), e2 = __expf(fa0.z), e3 = __expf(fa0.w);
    float e4 = __expf(fa1.x), e5 = __expf(fa1.y), e6 = __expf(fa1.z), e7 = __expf(fa1.w);
    ssum += (e0 + e1 + e2 + e3) + (e4 + e5 + e6 + e7);
    bf16x8 a, bb;
    a[0] = f2bf(e0); a[1] = f2bf(e1); a[2] = f2bf(e2); a[3] = f2bf(e3);
    a[4] = f2bf(e4); a[5] = f2bf(e5); a[6] = f2bf(e6); a[7] = f2bf(e7);
    bb[0] = f2bf(fb0.x); bb[1] = f2bf(fb0.y); bb[2] = f2bf(fb0.z); bb[3] = f2bf(fb0.w);
    bb[4] = f2bf(fb1.x); bb[5] = f2bf(fb1.y); bb[6] = f2bf(fb1.z); bb[7] = f2bf(fb1.w);
    acc = __builtin_amdgcn_mfma_f32_16x16x32_bf16(a, bb, acc, 0, 0, 0);
  }
  #pragma unroll
  for (int r = 0; r < 4; r++) {
    int k = half * 4 + r;
    atomicAdd(&lc[((size_t)b * 16 + k) * 64 + w * 16 + kr], acc[r]);
  }
  if (w == 0) {   // exp values identical across waves; only wave 0 contributes S
    ssum += __shfl_xor(ssum, 16);
    ssum += __shfl_xor(ssum, 32);
    if (lane < 16) atomicAdd(&S[b * 16 + kr], ssum);
  }
}

// ---------------- 4b) normalize lc by S OUTSIDE conv (VGPR-cliff protection) -------
__global__ __launch_bounds__(256) void k_lcnorm(
    float* __restrict__ lc, const float* __restrict__ S) {
  int i = blockIdx.x * 256 + threadIdx.x;   // 0..8191
  lc[i] /= S[i >> 6];
}

// ---------------- 5) MFMA implicit-im2col conv + fused epilogue (FROZEN) ----------
// R13 structure: E from global (L2-hot), 15.1KB LDS, 16-slot B-fragment ring,
// launch_bounds(256,2). Occupancy levers exhausted (R5/R10/R11 spilled; R13's
// LDS diet was occupancy-neutral -> issue-bound). Do not touch.
__global__ __launch_bounds__(256, 2) void k_conv_mfma(
    const float* __restrict__ proj, const ushort* __restrict__ etw,
    const float* __restrict__ qT, const float* __restrict__ lc,
    const uint* __restrict__ vhg,
    float* __restrict__ outT, float* __restrict__ out, int mode) {
  int s = blockIdx.x;      // 0..7
  int v = blockIdx.y;      // 0..63
  int b = blockIdx.z;
  int t = threadIdx.x;
  __shared__ __align__(16) ushort vh[86 * 88];       // 15136 B halo bf16

  if (mode != 0) {
    const uint4* vsrc = (const uint4*)(vhg + (size_t)b * NCH * NPIX + (size_t)v * VH_WORDS);
    uint4* vdst = (uint4*)vh;
    for (int i = t; i < 946; i += 256) vdst[i] = vsrc[i];
  } else {
    const float* vrow = proj + ((size_t)b * NCH + ROW_V + v) * NPIX;
    for (int i = t; i < 86 * 88; i += 256) {
      int hr = i / 88, hc = i % 88;
      int ir = hr - 11, ic = hc - 11;
      float val = (ir >= 0 && ir < 64 && ic >= 0 && ic < 64) ? vrow[ir * 64 + ic] : 0.f;
      unsigned u = __float_as_uint(val);
      vh[i] = (ushort)((u + 0x7fffu + ((u >> 16) & 1u)) >> 16);
    }
  }
  __syncthreads();

  int lane = t & 63, w = t >> 6;
  int n_ = lane & 15, q = lane >> 4;
  int rn = n_ >> 3, g = n_ & 7;

  f32x4 acc[8];
  #pragma unroll
  for (int i = 0; i < 8; i++) acc[i] = (f32x4)(0.f);

  const bf16x8* vh8 = (const bf16x8*)vh;
  const bf16x8* e8 = (const bf16x8*)etw + (size_t)s * 1472;  // global, L2-hot
  int baseA = (w * 16 + rn) * 11 + g + q;

  // prime circular fragment buffer with halo rows 0..15 (relative to baseA)
  bf16x8 bfr[16];
  #pragma unroll
  for (int r = 0; r < 16; r++)
    bfr[(r & 1) * 8 + ((r >> 1) & 7)] = vh8[baseA + r * 11];

  #pragma unroll
  for (int dy = 0; dy < 23; dy++) {
    bf16x8 ef = e8[dy * 64 + lane];
    // issue next row's read early; commit into the slot after this dy's MFMAs
    bf16x8 tmp;
    if (dy + 16 <= 36) tmp = vh8[baseA + (dy + 16) * 11];
    #pragma unroll
    for (int tt = 0; tt < 8; tt++) {
      int r = dy + 2 * tt;
      acc[tt] = __builtin_amdgcn_mfma_f32_16x16x32_bf16(
          ef, bfr[(r & 1) * 8 + ((r >> 1) & 7)], acc[tt], 0, 0, 0);
    }
    if (dy + 16 <= 36) {
      int rr = dy + 16;
      bfr[(rr & 1) * 8 + ((rr >> 1) & 7)] = tmp;
    }
  }

  float lcv[4];
  #pragma unroll
  for (int r = 0; r < 4; r++) lcv[r] = lc[((size_t)b * 16 + q * 4 + r) * 64 + v];

  if (mode != 0) {
    const float* qTb = qT + (size_t)b * 64 * NPIX;
    float* obT = outT + (size_t)b * 256 * NPIX;
    float* ob = out + (size_t)b * 256 * NPIX;
    #pragma unroll
    for (int tt = 0; tt < 8; tt++) {
      int row = w * 16 + 2 * tt + rn;
      int io = s * 512 + row * 8 + g;              // qT / outT index (coalesced)
      float lam[4];
      #pragma unroll
      for (int r = 0; r < 4; r++) lam[r] = acc[tt][r] + lcv[r];
      float y[4];
      #pragma unroll
      for (int h = 0; h < 4; h++) {
        float a = 0.f;
        #pragma unroll
        for (int r = 0; r < 4; r++)
          a += qTb[(size_t)(h * 16 + q * 4 + r) * NPIX + io] * lam[r];
        y[h] = a;
      }
      #pragma unroll
      for (int h = 0; h < 4; h++) {
        y[h] += __shfl_xor(y[h], 16);
        y[h] += __shfl_xor(y[h], 32);
      }
      if (q == 0) {
        if (mode == 2) {
          #pragma unroll
          for (int h = 0; h < 4; h++) obT[(size_t)(h * 64 + v) * NPIX + io] = y[h];
        } else {
          int p = row * 64 + 8 * g + s;
          #pragma unroll
          for (int h = 0; h < 4; h++) ob[(size_t)(h * 64 + v) * NPIX + p] = y[h];
        }
      }
    }
  } else {
    const float* qbp = proj + (size_t)b * NCH * NPIX;
    float* ob = out + (size_t)b * 256 * NPIX;
    #pragma unroll
    for (int tt = 0; tt < 8; tt++) {
      int p = (w * 16 + 2 * tt + rn) * 64 + 8 * g + s;
      float lam[4];
      #pragma unroll
      for (int r = 0; r < 4; r++) lam[r] = acc[tt][r] + lcv[r];
      float y[4];
      #pragma unroll
      for (int h = 0; h < 4; h++) {
        float a = 0.f;
        #pragma unroll
        for (int r = 0; r < 4; r++)
          a += qbp[(size_t)(h * 16 + q * 4 + r) * NPIX + p] * lam[r];
        y[h] = a;
      }
      #pragma unroll
      for (int h = 0; h < 4; h++) {
        y[h] += __shfl_xor(y[h], 16);
        y[h] += __shfl_xor(y[h], 32);
      }
      if (q == 0) {
        #pragma unroll
        for (int h = 0; h < 4; h++) ob[(size_t)(h * 64 + v) * NPIX + p] = y[h];
      }
    }
  }
}

// ---------------- 6) un-transpose: outT[b][ch][s*512+i] -> out[b][ch][p] ----------
__global__ __launch_bounds__(256) void k_outtrans(
    const float* __restrict__ outT, float* __restrict__ out) {
  int ch = blockIdx.x, b = blockIdx.y, t = threadIdx.x;
  __shared__ float buf[4608];
  const float* src = outT + ((size_t)b * 256 + ch) * NPIX;
  for (int it = 0; it < 16; it++) {
    int idx = it * 256 + t;           // s*512 + i
    int s = idx >> 9, i = idx & 511;
    int p = (i >> 3) * 64 + (i & 7) * 8 + s;
    buf[p + (p >> 3)] = src[idx];
  }
  __syncthreads();
  float* dst = out + ((size_t)b * 256 + ch) * NPIX;
  for (int it = 0; it < 16; it++) {
    int p = it * 256 + t;
    dst[p] = buf[p + (p >> 3)];
  }
}

extern "C" void kernel_launch(void* const* d_in, const int* in_sizes, int n_in,
                              void* d_out, int out_size, void* d_ws, size_t ws_size,
                              hipStream_t stream) {
  const float* x    = (const float*)d_in[0];
  const float* Wq   = (const float*)d_in[1];
  const float* qg   = (const float*)d_in[2];
  const float* qbta = (const float*)d_in[3];
  const float* qm   = (const float*)d_in[4];
  const float* qv   = (const float*)d_in[5];
  const float* Wk   = (const float*)d_in[6];
  const float* Wv   = (const float*)d_in[7];
  const float* vg   = (const float*)d_in[8];
  const float* vb   = (const float*)d_in[9];
  const float* vm   = (const float*)d_in[10];
  const float* vvar = (const float*)d_in[11];
  const float* emb  = (const float*)d_in[12];
  float* ws   = (float*)d_ws;
  float* Wt   = ws + WP_OFF;
  float* bp   = ws + BIAS_OFF;
  float* proj = ws + PROJ_OFF;
  float* Sw   = ws + RMAX_OFF;
  float* lcw  = ws + LC_OFF;
  ushort* etw = (ushort*)(ws + ET_OFF);
  float* qT   = ws + QT_OFF;
  float* outT = ws + OUTT_OFF;
  float* out  = (float*)d_out;
  uint* vhg   = (uint*)proj;      // proj q-row region (never materialized in mode>=1)
  ushort* wtA = (ushort*)out;     // d_out head: written by prep, read by projm,
                                  // both strictly before any out store

  size_t wsf = ws_size / sizeof(float);
  int mode = (wsf >= WS_NEED_FULL) ? 2 : ((wsf >= WS_NEED_QT) ? 1 : 0);

  hipLaunchKernelGGL(k_prep, dim3(mode >= 1 ? 2450 : 512), dim3(256), 0, stream,
                     Wq, qg, qbta, qm, qv, Wk, Wv, vg, vb, vm, vvar, emb,
                     Wt, bp, etw, wtA, vhg);
  hipMemsetAsync(Sw, 0, 8448 * sizeof(float), stream);   // S (256) + lc (8192)
  if (mode >= 1) {
    hipLaunchKernelGGL(k_projm, dim3(64, 8), dim3(256), 0, stream,
                       x, wtA, bp, proj, qT, vhg);
  } else {
    hipLaunchKernelGGL(k_proj, dim3(16, 8, 8), dim3(256), 0, stream, x, Wt, bp, proj);
  }
  hipLaunchKernelGGL(k_lambda_c, dim3(64, 8), dim3(256), 0, stream, proj, lcw, Sw);
  hipLaunchKernelGGL(k_lcnorm, dim3(32), dim3(256), 0, stream, lcw, Sw);
  hipLaunchKernelGGL(k_conv_mfma, dim3(8, 64, 8), dim3(256), 0, stream,
                     proj, etw, qT, lcw, vhg, outT, out, mode);
  if (mode == 2)
    hipLaunchKernelGGL(k_outtrans, dim3(256, 8), dim3(256), 0, stream, outT, out);
}